// Round 3
// baseline (1341.914 us; speedup 1.0000x reference)
//
#include <hip/hip_runtime.h>
#include <math.h>

#define N_NODES 20000
#define N_EDGES 320000
#define F_IN    128
#define E_IN    64
#define HID     64
#define NH      4
#define CH      64
#define HC      256   // NH*CH
#define L_LAYERS 4
#define OUT_DIM 32
#define NPB     16    // nodes per block in node_pre
#define NPO     8     // nodes per block in node_post

// ---------------- one-time: node encoder ----------------
__global__ __launch_bounds__(256) void node_enc(const float* __restrict__ x,
                                                const float* __restrict__ W,
                                                const float* __restrict__ b,
                                                float* __restrict__ h) {
    int base_node = blockIdx.x * 4;
    int t = threadIdx.x;
    __shared__ float xs[4][F_IN];
    for (int i = t; i < 4 * F_IN; i += 256) {
        int nn = base_node + i / F_IN;
        xs[i / F_IN][i % F_IN] = (nn < N_NODES) ? x[nn * F_IN + (i % F_IN)] : 0.f;
    }
    __syncthreads();
    int node = base_node + t / 64;
    int col  = t & 63;
    if (node >= N_NODES) return;
    float acc = b[col];
    const float* xr = xs[t / 64];
    for (int i = 0; i < F_IN; i++) acc += xr[i] * W[i * HID + col];
    h[node * HID + col] = acc;
}

// ---------------- CSR build with degree-descending node order ----------------
__global__ __launch_bounds__(256) void hist_dst(const int* __restrict__ dst,
                                                int* __restrict__ hist) {
    int e = blockIdx.x * 256 + threadIdx.x;
    if (e < N_EDGES) atomicAdd(&hist[dst[e]], 1);
}

__global__ __launch_bounds__(256) void bin_hist(const int* __restrict__ hist,
                                                int* __restrict__ bins) {
    int n = blockIdx.x * 256 + threadIdx.x;
    if (n >= N_NODES) return;
    int d = hist[n]; if (d > 255) d = 255;
    atomicAdd(&bins[d], 1);
}

// curb[b] = count of nodes in bins > b  (descending-degree rank start)
__global__ __launch_bounds__(256) void scan_bins(const int* __restrict__ bins,
                                                 int* __restrict__ curb) {
    __shared__ int s[256];
    int t = threadIdx.x;
    s[t] = bins[t];
    __syncthreads();
    int acc = 0;
    for (int b = t + 1; b < 256; b++) acc += s[b];
    curb[t] = acc;
}

__global__ __launch_bounds__(256) void assign_rank(const int* __restrict__ hist,
                                                   int* __restrict__ curb,
                                                   int* __restrict__ node_order,
                                                   int* __restrict__ rank_of,
                                                   int* __restrict__ deg_rank) {
    int n = blockIdx.x * 256 + threadIdx.x;
    if (n >= N_NODES) return;
    int d = hist[n];
    int b = d > 255 ? 255 : d;
    int r = atomicAdd(&curb[b], 1);
    node_order[r] = n;
    rank_of[n] = r;
    deg_rank[r] = d;
}

// single-block exclusive scan of arr[0..N) -> row_ptr[0..N], cursor[0..N)
__global__ __launch_bounds__(1024) void scan_hist(const int* __restrict__ arr,
                                                  int* __restrict__ row_ptr,
                                                  int* __restrict__ cursor) {
    __shared__ int sums[1024];
    const int CHUNK = 20;  // 1024*20 = 20480 >= 20000
    int t = threadIdx.x;
    int base = t * CHUNK;
    int local[CHUNK];
    int s = 0;
    for (int i = 0; i < CHUNK; i++) {
        int idx = base + i;
        int vv = (idx < N_NODES) ? arr[idx] : 0;
        local[i] = s;
        s += vv;
    }
    sums[t] = s;
    __syncthreads();
    for (int off = 1; off < 1024; off <<= 1) {
        int v = (t >= off) ? sums[t - off] : 0;
        __syncthreads();
        sums[t] += v;
        __syncthreads();
    }
    int excl = (t == 0) ? 0 : sums[t - 1];
    for (int i = 0; i < CHUNK; i++) {
        int idx = base + i;
        if (idx < N_NODES) {
            int p = excl + local[i];
            row_ptr[idx] = p;
            cursor[idx] = p;
        }
    }
    if (t == 1023) row_ptr[N_NODES] = sums[1023];
}

// one wave per edge: place src + raw edge_attr row into rank-grouped position
__global__ __launch_bounds__(256) void scatter_attr(const int* __restrict__ src,
                                                    const int* __restrict__ dst,
                                                    const int* __restrict__ rank_of,
                                                    int* __restrict__ cursor2,
                                                    const float* __restrict__ eattr,
                                                    int* __restrict__ src_perm,
                                                    float* __restrict__ attr_p) {
    int wave = threadIdx.x >> 6, lane = threadIdx.x & 63;
    int e = blockIdx.x * 4 + wave;
    if (e >= N_EDGES) return;
    int d = dst[e];
    int r = rank_of[d];
    int pos = 0;
    if (lane == 0) pos = atomicAdd(&cursor2[r], 1);
    pos = __shfl(pos, 0);
    if (lane == 0) src_perm[pos] = src[e];
    attr_p[(size_t)pos * E_IN + lane] = eattr[(size_t)e * E_IN + lane];
}

// ---------------- per-layer constants ----------------
// Wqe[l][i][h*64+j] = sum_c Wq[l][i][h*64+c]*We[l][j][h*64+c];  bqe analog with bq
__global__ __launch_bounds__(256) void make_wqe(const float* __restrict__ Wq,
                                                const float* __restrict__ bq,
                                                const float* __restrict__ We,
                                                float* __restrict__ Wqe,
                                                float* __restrict__ bqe) {
    int l = blockIdx.x / HID;
    int i = blockIdx.x % HID;
    int t = threadIdx.x;           // h*64+j
    int h = t >> 6, j = t & 63;
    const float* WqL = Wq + (size_t)l * HID * HC;
    const float* WeL = We + (size_t)l * HID * HC;
    float acc = 0.f;
    for (int c = 0; c < CH; c++)
        acc += WqL[i * HC + h * CH + c] * WeL[j * HC + h * CH + c];
    Wqe[(size_t)l * HID * HC + i * HC + t] = acc;
    if (i == 0) {
        const float* bqL = bq + l * HC;
        float accb = 0.f;
        for (int c = 0; c < CH; c++)
            accb += bqL[h * CH + c] * WeL[j * HC + h * CH + c];
        bqe[l * HC + t] = accb;
    }
}

// Wqe2[l][i][h*64+m] = sum_j Wqe[l][i][h*64+j]*eenc_W[m][j]; plus bqe2, wqb, bqb
__global__ __launch_bounds__(256) void make_wqe2(const float* __restrict__ Wqe,
                                                 const float* __restrict__ bqe,
                                                 const float* __restrict__ eW,
                                                 const float* __restrict__ eb,
                                                 float* __restrict__ Wqe2,
                                                 float* __restrict__ bqe2,
                                                 float* __restrict__ wqb,
                                                 float* __restrict__ bqb) {
    int l = blockIdx.x / HID, i = blockIdx.x % HID;
    int t = threadIdx.x;
    int h2 = t >> 6, m = t & 63;
    const float* Wr = Wqe + (size_t)l * HID * HC + i * HC + h2 * CH;  // [j]
    float acc = 0.f;
    for (int j = 0; j < HID; j++) acc += Wr[j] * eW[m * HID + j];
    Wqe2[(size_t)l * HID * HC + i * HC + t] = acc;
    if (m == 0) {
        float a = 0.f;
        for (int j = 0; j < HID; j++) a += Wr[j] * eb[j];
        wqb[l * HID * NH + i * NH + h2] = a;
    }
    if (i == 0) {
        const float* br = bqe + l * HC + h2 * CH;
        float a = 0.f;
        for (int j = 0; j < HID; j++) a += br[j] * eW[m * HID + j];
        bqe2[l * HC + t] = a;
        if (m == 0) {
            float bb = 0.f;
            for (int j = 0; j < HID; j++) bb += br[j] * eb[j];
            bqb[l * NH + h2] = bb;
        }
    }
}

// WeE[l][m][hc] = sum_j eenc_W[m][j]*We[l][j][hc];  beE[l][hc] = sum_j eenc_b[j]*We[l][j][hc]
__global__ __launch_bounds__(256) void make_weE(const float* __restrict__ eW,
                                                const float* __restrict__ eb,
                                                const float* __restrict__ We,
                                                float* __restrict__ WeE,
                                                float* __restrict__ beE) {
    int l = blockIdx.x / E_IN, m = blockIdx.x % E_IN;
    int t = threadIdx.x;
    const float* WeL = We + (size_t)l * HID * HC;
    float acc = 0.f;
    for (int j = 0; j < HID; j++) acc += eW[m * HID + j] * WeL[j * HC + t];
    WeE[(size_t)l * E_IN * HC + m * HC + t] = acc;
    if (m == 0) {
        float a = 0.f;
        for (int j = 0; j < HID; j++) a += eb[j] * WeL[j * HC + t];
        beE[l * HC + t] = a;
    }
}

// ---------------- per-layer node pre-pass ----------------
// z = (do_ln ? relu(LN(h)) : h)
// q,qw,k,v stored head-interleaved: buf[n][c*4+h]; skip planar; qb[n][4]
__global__ __launch_bounds__(256) void node_pre(const float* __restrict__ h,
        const float* __restrict__ Wq, const float* __restrict__ bq,
        const float* __restrict__ Wk, const float* __restrict__ bk,
        const float* __restrict__ Wv, const float* __restrict__ bv,
        const float* __restrict__ Wqe2, const float* __restrict__ bqe2,
        const float* __restrict__ wqb, const float* __restrict__ bqb,
        const float* __restrict__ Ws, const float* __restrict__ bs,
        const float* __restrict__ g, const float* __restrict__ be,
        int do_ln,
        float* __restrict__ q, float* __restrict__ k, float* __restrict__ v,
        float* __restrict__ qw, float* __restrict__ skip, float* __restrict__ qb) {
    int t = threadIdx.x;
    int base = blockIdx.x * NPB;
    int lane = t & 63;
    __shared__ float zs[NPB][HID];
    for (int it = 0; it < NPB / 4; it++) {
        int m = (t >> 6) + it * 4;
        int n = base + m;
        float val = (n < N_NODES) ? h[n * HID + lane] : 0.f;
        if (do_ln) {
            float mu = val;
            for (int o = 32; o > 0; o >>= 1) mu += __shfl_xor(mu, o);
            mu *= (1.f / 64.f);
            float d = val - mu;
            float var = d * d;
            for (int o = 32; o > 0; o >>= 1) var += __shfl_xor(var, o);
            var *= (1.f / 64.f);
            val = fmaxf(d * rsqrtf(var + 1e-5f) * g[lane] + be[lane], 0.f);
        }
        zs[m][lane] = val;
    }
    __syncthreads();
    float aq[NPB], ak[NPB], av[NPB], aw[NPB], as_[NPB];
    float bqv = bq[t], bkv = bk[t], bvv = bv[t], bwv = bqe2[t];
    float bsv = (t < 64) ? bs[t] : 0.f;
#pragma unroll
    for (int m = 0; m < NPB; m++) { aq[m]=bqv; ak[m]=bkv; av[m]=bvv; aw[m]=bwv; as_[m]=bsv; }
    for (int i = 0; i < HID; i++) {
        float wq = Wq[i * HC + t], wk = Wk[i * HC + t];
        float wv = Wv[i * HC + t], wqe = Wqe2[i * HC + t];
        float wsv = (t < 64) ? Ws[i * HID + t] : 0.f;
#pragma unroll
        for (int m = 0; m < NPB; m++) {
            float z = zs[m][i];
            aq[m] += z * wq; ak[m] += z * wk; av[m] += z * wv;
            aw[m] += z * wqe; as_[m] += z * wsv;
        }
    }
    int h_ = t >> 6, c = t & 63;
#pragma unroll
    for (int m = 0; m < NPB; m++) {
        int n = base + m;
        if (n >= N_NODES) break;
        size_t nb = (size_t)n * HC + c * 4 + h_;
        q[nb]  = aq[m];
        qw[nb] = aw[m];
        k[nb]  = ak[m];
        v[nb]  = av[m];
        if (t < 64) skip[n * HID + t] = as_[m];
    }
    // qb[n][h] = zs[n] . wqb[:,h] + bqb[h]   (wave 0 only)
    if (t < NPB * NH) {
        int m = t >> 2, h4 = t & 3;
        int n = base + m;
        if (n < N_NODES) {
            float a = bqb[h4];
            for (int i = 0; i < HID; i++) a += zs[m][i] * wqb[i * NH + h4];
            qb[n * NH + h4] = a;
        }
    }
}

// ---------------- per-layer edge gather (1 wave = 1 dst node, rank order) ----------------
__global__ __launch_bounds__(256) void gather_edges(
        const int* __restrict__ node_order, const int* __restrict__ new_rp,
        const int* __restrict__ src_perm, const float* __restrict__ attr_p,
        const float* __restrict__ k, const float* __restrict__ v,
        const float* __restrict__ qb,
        float* q_numv,      // in: q interleaved, out: numv planar [n][h*64+c]
        float* qw_numea,    // in: qw interleaved, out: numeat planar [n][h*64+m]
        float* __restrict__ den) {
    int wave = threadIdx.x >> 6;
    int lane = threadIdx.x & 63;
    int r = blockIdx.x * 4 + wave;
    if (r >= N_NODES) return;
    int n = node_order[r];
    int e0 = new_rp[r], e1 = new_rp[r + 1];
    size_t nb = (size_t)n * HC;
    const float4 qv = *(const float4*)(q_numv + nb + lane * 4);
    const float4 qwv = *(const float4*)(qw_numea + nb + lane * 4);
    const float4 qbv = *(const float4*)(qb + n * 4);
    float nv0 = 0.f, nv1 = 0.f, nv2 = 0.f, nv3 = 0.f;
    float ne0 = 0.f, ne1 = 0.f, ne2 = 0.f, ne3 = 0.f;
    float d0 = 0.f, d1 = 0.f, d2 = 0.f, d3 = 0.f;
#pragma unroll 2
    for (int e = e0; e < e1; e++) {
        int s_ = src_perm[e];
        float eaj = attr_p[(size_t)e * E_IN + lane];
        const float4 kk = *(const float4*)(k + (size_t)s_ * HC + lane * 4);
        const float4 vv = *(const float4*)(v + (size_t)s_ * HC + lane * 4);
        float r0 = fmaf(qv.x, kk.x, qwv.x * eaj);
        float r1 = fmaf(qv.y, kk.y, qwv.y * eaj);
        float r2 = fmaf(qv.z, kk.z, qwv.z * eaj);
        float r3 = fmaf(qv.w, kk.w, qwv.w * eaj);
        for (int o = 32; o > 0; o >>= 1) {
            r0 += __shfl_xor(r0, o);
            r1 += __shfl_xor(r1, o);
            r2 += __shfl_xor(r2, o);
            r3 += __shfl_xor(r3, o);
        }
        float ex0 = __expf((r0 + qbv.x) * 0.125f);
        float ex1 = __expf((r1 + qbv.y) * 0.125f);
        float ex2 = __expf((r2 + qbv.z) * 0.125f);
        float ex3 = __expf((r3 + qbv.w) * 0.125f);
        nv0 += ex0 * vv.x; nv1 += ex1 * vv.y; nv2 += ex2 * vv.z; nv3 += ex3 * vv.w;
        ne0 += ex0 * eaj;  ne1 += ex1 * eaj;  ne2 += ex2 * eaj;  ne3 += ex3 * eaj;
        d0 += ex0; d1 += ex1; d2 += ex2; d3 += ex3;
    }
    // overwrite q/qw rows (dead) with numerators, planar layout
    q_numv[nb + lane] = nv0;        q_numv[nb + 64 + lane] = nv1;
    q_numv[nb + 128 + lane] = nv2;  q_numv[nb + 192 + lane] = nv3;
    qw_numea[nb + lane] = ne0;        qw_numea[nb + 64 + lane] = ne1;
    qw_numea[nb + 128 + lane] = ne2;  qw_numea[nb + 192 + lane] = ne3;
    if (lane == 0) {
        den[n * 4 + 0] = d0; den[n * 4 + 1] = d1;
        den[n * 4 + 2] = d2; den[n * 4 + 3] = d3;
    }
}

// ---------------- per-layer node post-pass ----------------
// out[h][c] = (numv + numeat@WeE_head + den*beE) / (den+eps); h_new = mean_h + skip (+res)
__global__ __launch_bounds__(256) void node_post(
        const float* __restrict__ numv, const float* __restrict__ numeat,
        const float* __restrict__ den, const float* __restrict__ WeE,
        const float* __restrict__ beE,
        const float* __restrict__ skip, float* __restrict__ h, int add_res) {
    int t = threadIdx.x;
    int h_ = t >> 6;
    int base = blockIdx.x * NPO;
    __shared__ float nes[NPO][HC];
    __shared__ float vals[NPO][HC];
    for (int i = t; i < NPO * HC; i += 256) {
        int m = i >> 8;
        nes[m][i & 255] = numeat[(size_t)(base + m) * HC + (i & 255)];
    }
    __syncthreads();
    float acc[NPO];
#pragma unroll
    for (int m = 0; m < NPO; m++) acc[m] = 0.f;
    for (int j = 0; j < E_IN; j++) {
        float w = WeE[j * HC + t];
#pragma unroll
        for (int m = 0; m < NPO; m++) acc[m] += nes[m][h_ * CH + j] * w;
    }
    float bev = beE[t];
#pragma unroll
    for (int m = 0; m < NPO; m++) {
        int n = base + m;
        float dd = den[n * 4 + h_];
        vals[m][t] = (numv[(size_t)n * HC + t] + acc[m] + dd * bev) / (dd + 1e-16f) * 0.25f;
    }
    __syncthreads();
    for (int it = 0; it < 2; it++) {
        int idx = t + it * 256;          // 8 nodes x 64 ch
        int m = idx >> 6, c2 = idx & 63;
        int n = base + m;
        float s = vals[m][c2] + vals[m][64 + c2] + vals[m][128 + c2] + vals[m][192 + c2];
        float val = s + skip[n * HID + c2];
        if (add_res) val += h[n * HID + c2];
        h[n * HID + c2] = val;
    }
}

// ---------------- final head ----------------
__global__ __launch_bounds__(64) void final_head(const float* __restrict__ h,
                                                 const float* __restrict__ g,
                                                 const float* __restrict__ b,
                                                 const float* __restrict__ W,
                                                 const float* __restrict__ bias,
                                                 float* __restrict__ out) {
    int n = blockIdx.x;
    int t = threadIdx.x;  // 64
    float val = h[n * HID + t];
    float mu = val;
    for (int o = 32; o > 0; o >>= 1) mu += __shfl_xor(mu, o);
    mu *= (1.f / 64.f);
    float d = val - mu;
    float var = d * d;
    for (int o = 32; o > 0; o >>= 1) var += __shfl_xor(var, o);
    var *= (1.f / 64.f);
    float z = fmaxf(d * rsqrtf(var + 1e-5f) * g[t] + b[t], 0.f);
    __shared__ float zs[HID];
    zs[t] = z;
    __syncthreads();
    if (t < OUT_DIM) {
        float acc = bias[t];
        for (int i = 0; i < HID; i++) acc += zs[i] * W[i * OUT_DIM + t];
        out[n * OUT_DIM + t] = acc;
    }
}

extern "C" void kernel_launch(void* const* d_in, const int* in_sizes, int n_in,
                              void* d_out, int out_size, void* d_ws, size_t ws_size,
                              hipStream_t stream) {
    const float* x      = (const float*)d_in[0];
    const int*   ei     = (const int*)d_in[1];
    const float* eattr  = (const float*)d_in[2];
    const float* node_W = (const float*)d_in[3];
    const float* node_b = (const float*)d_in[4];
    const float* eenc_W = (const float*)d_in[5];
    const float* eenc_b = (const float*)d_in[6];
    const float* Wq     = (const float*)d_in[7];
    const float* bq     = (const float*)d_in[8];
    const float* Wk     = (const float*)d_in[9];
    const float* bk     = (const float*)d_in[10];
    const float* Wv     = (const float*)d_in[11];
    const float* bv     = (const float*)d_in[12];
    const float* We     = (const float*)d_in[13];
    const float* Wskip  = (const float*)d_in[14];
    const float* bskip  = (const float*)d_in[15];
    const float* ln_g   = (const float*)d_in[16];
    const float* ln_b   = (const float*)d_in[17];
    const float* lin_W  = (const float*)d_in[18];
    const float* lin_b  = (const float*)d_in[19];
    float* out = (float*)d_out;

    const int* src = ei;            // edge_index[0]
    const int* dst = ei + N_EDGES;  // edge_index[1]

    float* ws = (float*)d_ws;
    float* attr_p = ws; ws += (size_t)N_EDGES * E_IN;  // 20.48M floats
    float* Wqe    = attr_p;  // ALIAS: used only before scatter_attr runs
    float* h    = ws; ws += N_NODES * HID;
    float* q    = ws; ws += (size_t)N_NODES * HC;      // -> numv
    float* k    = ws; ws += (size_t)N_NODES * HC;
    float* v    = ws; ws += (size_t)N_NODES * HC;
    float* qw   = ws; ws += (size_t)N_NODES * HC;      // -> numeat
    float* skip = ws; ws += N_NODES * HID;
    float* den  = ws; ws += N_NODES * NH;
    float* qb   = ws; ws += N_NODES * NH;
    float* bqe  = ws; ws += L_LAYERS * HC;
    float* Wqe2 = ws; ws += (size_t)L_LAYERS * HID * HC;
    float* bqe2 = ws; ws += L_LAYERS * HC;
    float* wqb  = ws; ws += L_LAYERS * HID * NH;
    float* bqb  = ws; ws += L_LAYERS * NH;
    float* WeE  = ws; ws += (size_t)L_LAYERS * E_IN * HC;
    float* beE  = ws; ws += L_LAYERS * HC;
    int* ip = (int*)ws;
    int* hist       = ip; ip += N_NODES;
    int* bins       = ip; ip += 256;
    int* curb       = ip; ip += 256;
    int* node_order = ip; ip += N_NODES;
    int* rank_of    = ip; ip += N_NODES;
    int* deg_rank   = ip; ip += N_NODES;
    int* new_rp     = ip; ip += N_NODES + 4;
    int* cursor2    = ip; ip += N_NODES;
    int* src_perm   = ip; ip += N_EDGES;

    node_enc<<<(N_NODES + 3) / 4, 256, 0, stream>>>(x, node_W, node_b, h);

    hipMemsetAsync(hist, 0, N_NODES * sizeof(int), stream);
    hipMemsetAsync(bins, 0, 256 * sizeof(int), stream);
    hist_dst<<<(N_EDGES + 255) / 256, 256, 0, stream>>>(dst, hist);
    bin_hist<<<(N_NODES + 255) / 256, 256, 0, stream>>>(hist, bins);
    scan_bins<<<1, 256, 0, stream>>>(bins, curb);
    assign_rank<<<(N_NODES + 255) / 256, 256, 0, stream>>>(hist, curb, node_order,
                                                           rank_of, deg_rank);
    scan_hist<<<1, 1024, 0, stream>>>(deg_rank, new_rp, cursor2);

    // per-layer constants (Wqe aliases attr_p -> must finish before scatter_attr)
    make_wqe<<<L_LAYERS * HID, 256, 0, stream>>>(Wq, bq, We, Wqe, bqe);
    make_wqe2<<<L_LAYERS * HID, 256, 0, stream>>>(Wqe, bqe, eenc_W, eenc_b,
                                                  Wqe2, bqe2, wqb, bqb);
    make_weE<<<L_LAYERS * E_IN, 256, 0, stream>>>(eenc_W, eenc_b, We, WeE, beE);

    scatter_attr<<<(N_EDGES + 3) / 4, 256, 0, stream>>>(src, dst, rank_of, cursor2,
                                                        eattr, src_perm, attr_p);

    for (int l = 0; l < L_LAYERS; l++) {
        node_pre<<<(N_NODES + NPB - 1) / NPB, 256, 0, stream>>>(
            h,
            Wq + (size_t)l * HID * HC, bq + l * HC,
            Wk + (size_t)l * HID * HC, bk + l * HC,
            Wv + (size_t)l * HID * HC, bv + l * HC,
            Wqe2 + (size_t)l * HID * HC, bqe2 + l * HC,
            wqb + l * HID * NH, bqb + l * NH,
            Wskip + (size_t)l * HID * HID, bskip + l * HID,
            ln_g + l * HID, ln_b + l * HID,
            (l > 0) ? 1 : 0,
            q, k, v, qw, skip, qb);
        gather_edges<<<(N_NODES + 3) / 4, 256, 0, stream>>>(
            node_order, new_rp, src_perm, attr_p, k, v, qb, q, qw, den);
        node_post<<<(N_NODES + NPO - 1) / NPO, 256, 0, stream>>>(
            q, qw, den, WeE + (size_t)l * E_IN * HC, beE + l * HC,
            skip, h, (l > 0) ? 1 : 0);
    }

    final_head<<<N_NODES, 64, 0, stream>>>(h, ln_g, ln_b, lin_W, lin_b, out);
}

// Round 4
// 1217.725 us; speedup vs baseline: 1.1020x; 1.1020x over previous
//
#include <hip/hip_runtime.h>
#include <math.h>

#define N_NODES 20000
#define N_EDGES 320000
#define F_IN    128
#define E_IN    64
#define HID     64
#define NH      4
#define CH      64
#define HC      256   // NH*CH
#define L_LAYERS 4
#define OUT_DIM 32
#define NPB     16    // nodes per block in node_pre
#define NPO     8     // nodes per block in node_post

// ---------------- one-time: node encoder ----------------
__global__ __launch_bounds__(256) void node_enc(const float* __restrict__ x,
                                                const float* __restrict__ W,
                                                const float* __restrict__ b,
                                                float* __restrict__ h) {
    int base_node = blockIdx.x * 4;
    int t = threadIdx.x;
    __shared__ float xs[4][F_IN];
    for (int i = t; i < 4 * F_IN; i += 256) {
        int nn = base_node + i / F_IN;
        xs[i / F_IN][i % F_IN] = (nn < N_NODES) ? x[nn * F_IN + (i % F_IN)] : 0.f;
    }
    __syncthreads();
    int node = base_node + t / 64;
    int col  = t & 63;
    if (node >= N_NODES) return;
    float acc = b[col];
    const float* xr = xs[t / 64];
    for (int i = 0; i < F_IN; i++) acc += xr[i] * W[i * HID + col];
    h[node * HID + col] = acc;
}

// ---------------- CSR build with degree-descending node order ----------------
__global__ __launch_bounds__(256) void hist_dst(const int* __restrict__ dst,
                                                int* __restrict__ hist) {
    int e = blockIdx.x * 256 + threadIdx.x;
    if (e < N_EDGES) atomicAdd(&hist[dst[e]], 1);
}

__global__ __launch_bounds__(256) void bin_hist(const int* __restrict__ hist,
                                                int* __restrict__ bins) {
    int n = blockIdx.x * 256 + threadIdx.x;
    if (n >= N_NODES) return;
    int d = hist[n]; if (d > 255) d = 255;
    atomicAdd(&bins[d], 1);
}

// curb[b] = count of nodes in bins > b  (descending-degree rank start)
__global__ __launch_bounds__(256) void scan_bins(const int* __restrict__ bins,
                                                 int* __restrict__ curb) {
    __shared__ int s[256];
    int t = threadIdx.x;
    s[t] = bins[t];
    __syncthreads();
    int acc = 0;
    for (int b = t + 1; b < 256; b++) acc += s[b];
    curb[t] = acc;
}

__global__ __launch_bounds__(256) void assign_rank(const int* __restrict__ hist,
                                                   int* __restrict__ curb,
                                                   int* __restrict__ node_order,
                                                   int* __restrict__ rank_of,
                                                   int* __restrict__ deg_rank) {
    int n = blockIdx.x * 256 + threadIdx.x;
    if (n >= N_NODES) return;
    int d = hist[n];
    int b = d > 255 ? 255 : d;
    int r = atomicAdd(&curb[b], 1);
    node_order[r] = n;
    rank_of[n] = r;
    deg_rank[r] = d;
}

// single-block exclusive scan of arr[0..N) -> row_ptr[0..N], cursor[0..N)
__global__ __launch_bounds__(1024) void scan_hist(const int* __restrict__ arr,
                                                  int* __restrict__ row_ptr,
                                                  int* __restrict__ cursor) {
    __shared__ int sums[1024];
    const int CHUNK = 20;  // 1024*20 = 20480 >= 20000
    int t = threadIdx.x;
    int base = t * CHUNK;
    int local[CHUNK];
    int s = 0;
    for (int i = 0; i < CHUNK; i++) {
        int idx = base + i;
        int vv = (idx < N_NODES) ? arr[idx] : 0;
        local[i] = s;
        s += vv;
    }
    sums[t] = s;
    __syncthreads();
    for (int off = 1; off < 1024; off <<= 1) {
        int v = (t >= off) ? sums[t - off] : 0;
        __syncthreads();
        sums[t] += v;
        __syncthreads();
    }
    int excl = (t == 0) ? 0 : sums[t - 1];
    for (int i = 0; i < CHUNK; i++) {
        int idx = base + i;
        if (idx < N_NODES) {
            int p = excl + local[i];
            row_ptr[idx] = p;
            cursor[idx] = p;
        }
    }
    if (t == 1023) row_ptr[N_NODES] = sums[1023];
}

// phase A: positions only (int traffic)
__global__ __launch_bounds__(256) void compute_pos(const int* __restrict__ src,
                                                   const int* __restrict__ dst,
                                                   const int* __restrict__ rank_of,
                                                   int* __restrict__ cursor2,
                                                   int* __restrict__ eid_of,
                                                   int* __restrict__ srcrank_perm) {
    int e = blockIdx.x * 256 + threadIdx.x;
    if (e >= N_EDGES) return;
    int r = rank_of[dst[e]];
    int pos = atomicAdd(&cursor2[r], 1);
    eid_of[pos] = e;
    srcrank_perm[pos] = rank_of[src[e]];
}

// phase B: gather-form attr permute — random reads, coalesced writes
__global__ __launch_bounds__(256) void permute_attr(const int* __restrict__ eid_of,
                                                    const float* __restrict__ eattr,
                                                    float* __restrict__ attr_p) {
    int t = threadIdx.x;
    int wave = t >> 6, lane = t & 63;
    int p = blockIdx.x * 16 + wave * 4 + (lane >> 4);
    if (p >= N_EDGES) return;
    int e = eid_of[p];
    int qi = (lane & 15) * 4;
    *(float4*)(attr_p + (size_t)p * E_IN + qi) =
        *(const float4*)(eattr + (size_t)e * E_IN + qi);
}

// ---------------- per-layer constants ----------------
__global__ __launch_bounds__(256) void make_wqe(const float* __restrict__ Wq,
                                                const float* __restrict__ bq,
                                                const float* __restrict__ We,
                                                float* __restrict__ Wqe,
                                                float* __restrict__ bqe) {
    int l = blockIdx.x / HID;
    int i = blockIdx.x % HID;
    int t = threadIdx.x;           // h*64+j
    int h = t >> 6, j = t & 63;
    const float* WqL = Wq + (size_t)l * HID * HC;
    const float* WeL = We + (size_t)l * HID * HC;
    float acc = 0.f;
    for (int c = 0; c < CH; c++)
        acc += WqL[i * HC + h * CH + c] * WeL[j * HC + h * CH + c];
    Wqe[(size_t)l * HID * HC + i * HC + t] = acc;
    if (i == 0) {
        const float* bqL = bq + l * HC;
        float accb = 0.f;
        for (int c = 0; c < CH; c++)
            accb += bqL[h * CH + c] * WeL[j * HC + h * CH + c];
        bqe[l * HC + t] = accb;
    }
}

__global__ __launch_bounds__(256) void make_wqe2(const float* __restrict__ Wqe,
                                                 const float* __restrict__ bqe,
                                                 const float* __restrict__ eW,
                                                 const float* __restrict__ eb,
                                                 float* __restrict__ Wqe2,
                                                 float* __restrict__ bqe2,
                                                 float* __restrict__ wqb,
                                                 float* __restrict__ bqb) {
    int l = blockIdx.x / HID, i = blockIdx.x % HID;
    int t = threadIdx.x;
    int h2 = t >> 6, m = t & 63;
    const float* Wr = Wqe + (size_t)l * HID * HC + i * HC + h2 * CH;  // [j]
    float acc = 0.f;
    for (int j = 0; j < HID; j++) acc += Wr[j] * eW[m * HID + j];
    Wqe2[(size_t)l * HID * HC + i * HC + t] = acc;
    if (m == 0) {
        float a = 0.f;
        for (int j = 0; j < HID; j++) a += Wr[j] * eb[j];
        wqb[l * HID * NH + i * NH + h2] = a;
    }
    if (i == 0) {
        const float* br = bqe + l * HC + h2 * CH;
        float a = 0.f;
        for (int j = 0; j < HID; j++) a += br[j] * eW[m * HID + j];
        bqe2[l * HC + t] = a;
        if (m == 0) {
            float bb = 0.f;
            for (int j = 0; j < HID; j++) bb += br[j] * eb[j];
            bqb[l * NH + h2] = bb;
        }
    }
}

__global__ __launch_bounds__(256) void make_weE(const float* __restrict__ eW,
                                                const float* __restrict__ eb,
                                                const float* __restrict__ We,
                                                float* __restrict__ WeE,
                                                float* __restrict__ beE) {
    int l = blockIdx.x / E_IN, m = blockIdx.x % E_IN;
    int t = threadIdx.x;
    const float* WeL = We + (size_t)l * HID * HC;
    float acc = 0.f;
    for (int j = 0; j < HID; j++) acc += eW[m * HID + j] * WeL[j * HC + t];
    WeE[(size_t)l * E_IN * HC + m * HC + t] = acc;
    if (m == 0) {
        float a = 0.f;
        for (int j = 0; j < HID; j++) a += eb[j] * WeL[j * HC + t];
        beE[l * HC + t] = a;
    }
}

// ---------------- per-layer node pre-pass (rank-indexed outputs, planar) ----------------
__global__ __launch_bounds__(256) void node_pre(const float* __restrict__ h,
        const int* __restrict__ node_order,
        const float* __restrict__ Wq, const float* __restrict__ bq,
        const float* __restrict__ Wk, const float* __restrict__ bk,
        const float* __restrict__ Wv, const float* __restrict__ bv,
        const float* __restrict__ Wqe2, const float* __restrict__ bqe2,
        const float* __restrict__ wqb, const float* __restrict__ bqb,
        const float* __restrict__ Ws, const float* __restrict__ bs,
        const float* __restrict__ g, const float* __restrict__ be,
        int do_ln,
        float* __restrict__ q, float* __restrict__ k, float* __restrict__ v,
        float* __restrict__ qw, float* __restrict__ skip, float* __restrict__ qb) {
    int t = threadIdx.x;
    int base = blockIdx.x * NPB;
    int lane = t & 63;
    __shared__ float zs[NPB][HID];
    __shared__ int nord[NPB];
    if (t < NPB) {
        int r = base + t;
        nord[t] = (r < N_NODES) ? node_order[r] : 0;
    }
    __syncthreads();
    for (int it = 0; it < NPB / 4; it++) {
        int m = (t >> 6) + it * 4;
        int r = base + m;
        float val = (r < N_NODES) ? h[nord[m] * HID + lane] : 0.f;
        if (do_ln) {
            float mu = val;
            for (int o = 32; o > 0; o >>= 1) mu += __shfl_xor(mu, o);
            mu *= (1.f / 64.f);
            float d = val - mu;
            float var = d * d;
            for (int o = 32; o > 0; o >>= 1) var += __shfl_xor(var, o);
            var *= (1.f / 64.f);
            val = fmaxf(d * rsqrtf(var + 1e-5f) * g[lane] + be[lane], 0.f);
        }
        zs[m][lane] = val;
    }
    __syncthreads();
    float aq[NPB], ak[NPB], av[NPB], aw[NPB], as_[NPB];
    float bqv = bq[t], bkv = bk[t], bvv = bv[t], bwv = bqe2[t];
    float bsv = (t < 64) ? bs[t] : 0.f;
#pragma unroll
    for (int m = 0; m < NPB; m++) { aq[m]=bqv; ak[m]=bkv; av[m]=bvv; aw[m]=bwv; as_[m]=bsv; }
    for (int i = 0; i < HID; i++) {
        float wq = Wq[i * HC + t], wk = Wk[i * HC + t];
        float wv = Wv[i * HC + t], wqe = Wqe2[i * HC + t];
        float wsv = (t < 64) ? Ws[i * HID + t] : 0.f;
#pragma unroll
        for (int m = 0; m < NPB; m++) {
            float z = zs[m][i];
            aq[m] += z * wq; ak[m] += z * wk; av[m] += z * wv;
            aw[m] += z * wqe; as_[m] += z * wsv;
        }
    }
#pragma unroll
    for (int m = 0; m < NPB; m++) {
        int r = base + m;
        if (r >= N_NODES) break;
        size_t rb = (size_t)r * HC + t;   // planar
        q[rb]  = aq[m];
        qw[rb] = aw[m];
        k[rb]  = ak[m];
        v[rb]  = av[m];
        if (t < 64) skip[r * HID + t] = as_[m];
    }
    // qb[r][h] = zs . wqb[:,h] + bqb[h]
    if (t < NPB * NH) {
        int m = t >> 2, h4 = t & 3;
        int r = base + m;
        if (r < N_NODES) {
            float a = bqb[h4];
            for (int i = 0; i < HID; i++) a += zs[m][i] * wqb[i * NH + h4];
            qb[r * NH + h4] = a;
        }
    }
}

// ---------------- per-layer edge gather: 1 wave = 1 rank; quarter-wave = 1 head ----
// lane = h*16+i holds channels c = i*4..i*4+3 of head h (planar float4)
__global__ __launch_bounds__(256) void gather_edges(
        const int* __restrict__ new_rp,
        const int* __restrict__ srcrank_perm, const float* __restrict__ attr_p,
        const float* __restrict__ k, const float* __restrict__ v,
        const float* __restrict__ qb,
        float* q_numv,      // in: q planar, out: numv planar
        float* qw_numea,    // in: qw planar, out: numea planar
        float* __restrict__ den) {
    int wave = threadIdx.x >> 6;
    int lane = threadIdx.x & 63;
    int r = blockIdx.x * 4 + wave;
    if (r >= N_NODES) return;
    int e0 = new_rp[r], e1 = new_rp[r + 1];
    size_t nb = (size_t)r * HC;
    int qi = (lane & 15) * 4;
    int head = lane >> 4;
    const float4 qv4 = *(const float4*)(q_numv + nb + lane * 4);
    const float4 qw4 = *(const float4*)(qw_numea + nb + lane * 4);
    float qbh = qb[r * NH + head];
    float4 nv = make_float4(0.f, 0.f, 0.f, 0.f);
    float4 ne = make_float4(0.f, 0.f, 0.f, 0.f);
    float dsum = 0.f;
    for (int e = e0; e < e1; e++) {
        int s_ = srcrank_perm[e];
        const float4 at = *(const float4*)(attr_p + (size_t)e * E_IN + qi);
        const float4 kk = *(const float4*)(k + (size_t)s_ * HC + lane * 4);
        const float4 vv = *(const float4*)(v + (size_t)s_ * HC + lane * 4);
        float rr = qv4.x * kk.x + qv4.y * kk.y + qv4.z * kk.z + qv4.w * kk.w
                 + qw4.x * at.x + qw4.y * at.y + qw4.z * at.z + qw4.w * at.w;
        rr += __shfl_xor(rr, 1);   // masks < 16 stay within the quarter-wave
        rr += __shfl_xor(rr, 2);
        rr += __shfl_xor(rr, 4);
        rr += __shfl_xor(rr, 8);
        float ex = __expf((rr + qbh) * 0.125f);
        nv.x += ex * vv.x; nv.y += ex * vv.y; nv.z += ex * vv.z; nv.w += ex * vv.w;
        ne.x += ex * at.x; ne.y += ex * at.y; ne.z += ex * at.z; ne.w += ex * at.w;
        dsum += ex;
    }
    *(float4*)(q_numv + nb + lane * 4) = nv;
    *(float4*)(qw_numea + nb + lane * 4) = ne;
    if ((lane & 15) == 0) den[r * NH + head] = dsum;
}

// ---------------- per-layer node post-pass (rank-indexed inputs) ----------------
__global__ __launch_bounds__(256) void node_post(
        const int* __restrict__ node_order,
        const float* __restrict__ numv, const float* __restrict__ numeat,
        const float* __restrict__ den, const float* __restrict__ WeE,
        const float* __restrict__ beE,
        const float* __restrict__ skip, float* __restrict__ h, int add_res) {
    int t = threadIdx.x;
    int h_ = t >> 6;
    int base = blockIdx.x * NPO;
    __shared__ float nes[NPO][HC];
    __shared__ float vals[NPO][HC];
    __shared__ int nord[NPO];
    if (t < NPO) {
        int r = base + t;
        nord[t] = (r < N_NODES) ? node_order[r] : 0;
    }
    for (int i = t; i < NPO * HC; i += 256) {
        int m = i >> 8;
        nes[m][i & 255] = numeat[(size_t)(base + m) * HC + (i & 255)];
    }
    __syncthreads();
    float acc[NPO];
#pragma unroll
    for (int m = 0; m < NPO; m++) acc[m] = 0.f;
    for (int j = 0; j < E_IN; j++) {
        float w = WeE[j * HC + t];
#pragma unroll
        for (int m = 0; m < NPO; m++) acc[m] += nes[m][h_ * CH + j] * w;
    }
    float bev = beE[t];
#pragma unroll
    for (int m = 0; m < NPO; m++) {
        int r = base + m;
        float dd = den[r * NH + h_];
        vals[m][t] = (numv[(size_t)r * HC + t] + acc[m] + dd * bev) / (dd + 1e-16f) * 0.25f;
    }
    __syncthreads();
    for (int it = 0; it < 2; it++) {
        int idx = t + it * 256;          // 8 nodes x 64 ch
        int m = idx >> 6, c2 = idx & 63;
        int r = base + m;
        if (r >= N_NODES) continue;
        int n = nord[m];
        float s = vals[m][c2] + vals[m][64 + c2] + vals[m][128 + c2] + vals[m][192 + c2];
        float val = s + skip[r * HID + c2];
        if (add_res) val += h[n * HID + c2];
        h[n * HID + c2] = val;
    }
}

// ---------------- final head ----------------
__global__ __launch_bounds__(64) void final_head(const float* __restrict__ h,
                                                 const float* __restrict__ g,
                                                 const float* __restrict__ b,
                                                 const float* __restrict__ W,
                                                 const float* __restrict__ bias,
                                                 float* __restrict__ out) {
    int n = blockIdx.x;
    int t = threadIdx.x;  // 64
    float val = h[n * HID + t];
    float mu = val;
    for (int o = 32; o > 0; o >>= 1) mu += __shfl_xor(mu, o);
    mu *= (1.f / 64.f);
    float d = val - mu;
    float var = d * d;
    for (int o = 32; o > 0; o >>= 1) var += __shfl_xor(var, o);
    var *= (1.f / 64.f);
    float z = fmaxf(d * rsqrtf(var + 1e-5f) * g[t] + b[t], 0.f);
    __shared__ float zs[HID];
    zs[t] = z;
    __syncthreads();
    if (t < OUT_DIM) {
        float acc = bias[t];
        for (int i = 0; i < HID; i++) acc += zs[i] * W[i * OUT_DIM + t];
        out[n * OUT_DIM + t] = acc;
    }
}

extern "C" void kernel_launch(void* const* d_in, const int* in_sizes, int n_in,
                              void* d_out, int out_size, void* d_ws, size_t ws_size,
                              hipStream_t stream) {
    const float* x      = (const float*)d_in[0];
    const int*   ei     = (const int*)d_in[1];
    const float* eattr  = (const float*)d_in[2];
    const float* node_W = (const float*)d_in[3];
    const float* node_b = (const float*)d_in[4];
    const float* eenc_W = (const float*)d_in[5];
    const float* eenc_b = (const float*)d_in[6];
    const float* Wq     = (const float*)d_in[7];
    const float* bq     = (const float*)d_in[8];
    const float* Wk     = (const float*)d_in[9];
    const float* bk     = (const float*)d_in[10];
    const float* Wv     = (const float*)d_in[11];
    const float* bv     = (const float*)d_in[12];
    const float* We     = (const float*)d_in[13];
    const float* Wskip  = (const float*)d_in[14];
    const float* bskip  = (const float*)d_in[15];
    const float* ln_g   = (const float*)d_in[16];
    const float* ln_b   = (const float*)d_in[17];
    const float* lin_W  = (const float*)d_in[18];
    const float* lin_b  = (const float*)d_in[19];
    float* out = (float*)d_out;

    const int* src = ei;            // edge_index[0]
    const int* dst = ei + N_EDGES;  // edge_index[1]

    float* ws = (float*)d_ws;
    float* attr_p = ws; ws += (size_t)N_EDGES * E_IN;  // 20.48M floats
    float* Wqe    = attr_p;  // ALIAS: dead before permute_attr runs
    float* h    = ws; ws += N_NODES * HID;
    float* q    = ws; ws += (size_t)N_NODES * HC;      // -> numv (rank-indexed)
    float* k    = ws; ws += (size_t)N_NODES * HC;      // rank-indexed
    float* v    = ws; ws += (size_t)N_NODES * HC;      // rank-indexed
    float* qw   = ws; ws += (size_t)N_NODES * HC;      // -> numeat (rank-indexed)
    float* skip = ws; ws += N_NODES * HID;             // rank-indexed
    float* den  = ws; ws += N_NODES * NH;              // rank-indexed
    float* qb   = ws; ws += N_NODES * NH;              // rank-indexed
    float* bqe  = ws; ws += L_LAYERS * HC;
    float* Wqe2 = ws; ws += (size_t)L_LAYERS * HID * HC;
    float* bqe2 = ws; ws += L_LAYERS * HC;
    float* wqb  = ws; ws += L_LAYERS * HID * NH;
    float* bqb  = ws; ws += L_LAYERS * NH;
    float* WeE  = ws; ws += (size_t)L_LAYERS * E_IN * HC;
    float* beE  = ws; ws += L_LAYERS * HC;
    int* ip = (int*)ws;
    int* hist         = ip; ip += N_NODES;
    int* bins         = ip; ip += 256;
    int* curb         = ip; ip += 256;
    int* node_order   = ip; ip += N_NODES;
    int* rank_of      = ip; ip += N_NODES;
    int* deg_rank     = ip; ip += N_NODES;
    int* new_rp       = ip; ip += N_NODES + 4;
    int* cursor2      = ip; ip += N_NODES;
    int* srcrank_perm = ip; ip += N_EDGES;
    int* eid_of       = ip; ip += N_EDGES;

    node_enc<<<(N_NODES + 3) / 4, 256, 0, stream>>>(x, node_W, node_b, h);

    hipMemsetAsync(hist, 0, N_NODES * sizeof(int), stream);
    hipMemsetAsync(bins, 0, 256 * sizeof(int), stream);
    hist_dst<<<(N_EDGES + 255) / 256, 256, 0, stream>>>(dst, hist);
    bin_hist<<<(N_NODES + 255) / 256, 256, 0, stream>>>(hist, bins);
    scan_bins<<<1, 256, 0, stream>>>(bins, curb);
    assign_rank<<<(N_NODES + 255) / 256, 256, 0, stream>>>(hist, curb, node_order,
                                                           rank_of, deg_rank);
    scan_hist<<<1, 1024, 0, stream>>>(deg_rank, new_rp, cursor2);

    // per-layer constants (Wqe aliases attr_p -> must finish before permute_attr)
    make_wqe<<<L_LAYERS * HID, 256, 0, stream>>>(Wq, bq, We, Wqe, bqe);
    make_wqe2<<<L_LAYERS * HID, 256, 0, stream>>>(Wqe, bqe, eenc_W, eenc_b,
                                                  Wqe2, bqe2, wqb, bqb);
    make_weE<<<L_LAYERS * E_IN, 256, 0, stream>>>(eenc_W, eenc_b, We, WeE, beE);

    compute_pos<<<(N_EDGES + 255) / 256, 256, 0, stream>>>(src, dst, rank_of, cursor2,
                                                           eid_of, srcrank_perm);
    permute_attr<<<N_EDGES / 16, 256, 0, stream>>>(eid_of, eattr, attr_p);

    for (int l = 0; l < L_LAYERS; l++) {
        node_pre<<<(N_NODES + NPB - 1) / NPB, 256, 0, stream>>>(
            h, node_order,
            Wq + (size_t)l * HID * HC, bq + l * HC,
            Wk + (size_t)l * HID * HC, bk + l * HC,
            Wv + (size_t)l * HID * HC, bv + l * HC,
            Wqe2 + (size_t)l * HID * HC, bqe2 + l * HC,
            wqb + l * HID * NH, bqb + l * NH,
            Wskip + (size_t)l * HID * HID, bskip + l * HID,
            ln_g + l * HID, ln_b + l * HID,
            (l > 0) ? 1 : 0,
            q, k, v, qw, skip, qb);
        gather_edges<<<(N_NODES + 3) / 4, 256, 0, stream>>>(
            new_rp, srcrank_perm, attr_p, k, v, qb, q, qw, den);
        node_post<<<(N_NODES + NPO - 1) / NPO, 256, 0, stream>>>(
            node_order, q, qw, den, WeE + (size_t)l * E_IN * HC, beE + l * HC,
            skip, h, (l > 0) ? 1 : 0);
    }

    final_head<<<N_NODES, 64, 0, stream>>>(h, ln_g, ln_b, lin_W, lin_b, out);
}

// Round 5
// 1019.540 us; speedup vs baseline: 1.3162x; 1.1944x over previous
//
#include <hip/hip_runtime.h>
#include <hip/hip_fp16.h>
#include <math.h>

#define N_NODES 20000
#define N_EDGES 320000
#define F_IN    128
#define E_IN    64
#define HID     64
#define NH      4
#define CH      64
#define HC      256   // NH*CH
#define L_LAYERS 4
#define OUT_DIM 32
#define NPB     16    // nodes per block in node_pre
#define NPO     8     // nodes per block in node_post

// ---------------- one-time: node encoder ----------------
__global__ __launch_bounds__(256) void node_enc(const float* __restrict__ x,
                                                const float* __restrict__ W,
                                                const float* __restrict__ b,
                                                float* __restrict__ h) {
    int base_node = blockIdx.x * 4;
    int t = threadIdx.x;
    __shared__ float xs[4][F_IN];
    for (int i = t; i < 4 * F_IN; i += 256) {
        int nn = base_node + i / F_IN;
        xs[i / F_IN][i % F_IN] = (nn < N_NODES) ? x[nn * F_IN + (i % F_IN)] : 0.f;
    }
    __syncthreads();
    int node = base_node + t / 64;
    int col  = t & 63;
    if (node >= N_NODES) return;
    float acc = b[col];
    const float* xr = xs[t / 64];
    for (int i = 0; i < F_IN; i++) acc += xr[i] * W[i * HID + col];
    h[node * HID + col] = acc;
}

// ---------------- CSR build with degree-descending node order ----------------
__global__ __launch_bounds__(256) void hist_dst(const int* __restrict__ dst,
                                                int* __restrict__ hist) {
    int e = blockIdx.x * 256 + threadIdx.x;
    if (e < N_EDGES) atomicAdd(&hist[dst[e]], 1);
}

__global__ __launch_bounds__(256) void bin_hist(const int* __restrict__ hist,
                                                int* __restrict__ bins) {
    int n = blockIdx.x * 256 + threadIdx.x;
    if (n >= N_NODES) return;
    int d = hist[n]; if (d > 255) d = 255;
    atomicAdd(&bins[d], 1);
}

// curb[b] = count of nodes in bins > b  (descending-degree rank start)
__global__ __launch_bounds__(256) void scan_bins(const int* __restrict__ bins,
                                                 int* __restrict__ curb) {
    __shared__ int s[256];
    int t = threadIdx.x;
    s[t] = bins[t];
    __syncthreads();
    int acc = 0;
    for (int b = t + 1; b < 256; b++) acc += s[b];
    curb[t] = acc;
}

__global__ __launch_bounds__(256) void assign_rank(const int* __restrict__ hist,
                                                   int* __restrict__ curb,
                                                   int* __restrict__ node_order,
                                                   int* __restrict__ rank_of,
                                                   int* __restrict__ deg_rank) {
    int n = blockIdx.x * 256 + threadIdx.x;
    if (n >= N_NODES) return;
    int d = hist[n];
    int b = d > 255 ? 255 : d;
    int r = atomicAdd(&curb[b], 1);
    node_order[r] = n;
    rank_of[n] = r;
    deg_rank[r] = d;
}

// single-block exclusive scan of arr[0..N) -> row_ptr[0..N], cursor[0..N)
__global__ __launch_bounds__(1024) void scan_hist(const int* __restrict__ arr,
                                                  int* __restrict__ row_ptr,
                                                  int* __restrict__ cursor) {
    __shared__ int sums[1024];
    const int CHUNK = 20;  // 1024*20 = 20480 >= 20000
    int t = threadIdx.x;
    int base = t * CHUNK;
    int local[CHUNK];
    int s = 0;
    for (int i = 0; i < CHUNK; i++) {
        int idx = base + i;
        int vv = (idx < N_NODES) ? arr[idx] : 0;
        local[i] = s;
        s += vv;
    }
    sums[t] = s;
    __syncthreads();
    for (int off = 1; off < 1024; off <<= 1) {
        int v = (t >= off) ? sums[t - off] : 0;
        __syncthreads();
        sums[t] += v;
        __syncthreads();
    }
    int excl = (t == 0) ? 0 : sums[t - 1];
    for (int i = 0; i < CHUNK; i++) {
        int idx = base + i;
        if (idx < N_NODES) {
            int p = excl + local[i];
            row_ptr[idx] = p;
            cursor[idx] = p;
        }
    }
    if (t == 1023) row_ptr[N_NODES] = sums[1023];
}

// phase A: positions only (int traffic)
__global__ __launch_bounds__(256) void compute_pos(const int* __restrict__ src,
                                                   const int* __restrict__ dst,
                                                   const int* __restrict__ rank_of,
                                                   int* __restrict__ cursor2,
                                                   int* __restrict__ eid_of,
                                                   int* __restrict__ srcrank_perm) {
    int e = blockIdx.x * 256 + threadIdx.x;
    if (e >= N_EDGES) return;
    int r = rank_of[dst[e]];
    int pos = atomicAdd(&cursor2[r], 1);
    eid_of[pos] = e;
    srcrank_perm[pos] = rank_of[src[e]];
}

// phase B: gather-form attr permute + fp16 convert — random reads, coalesced writes
__global__ __launch_bounds__(256) void permute_attr(const int* __restrict__ eid_of,
                                                    const float* __restrict__ eattr,
                                                    __half* __restrict__ attr_p) {
    int t = threadIdx.x;
    int wave = t >> 6, lane = t & 63;
    int p = blockIdx.x * 16 + wave * 4 + (lane >> 4);
    if (p >= N_EDGES) return;
    int e = eid_of[p];
    int qi = (lane & 15) * 4;
    float4 a = *(const float4*)(eattr + (size_t)e * E_IN + qi);
    __half2 h0 = __floats2half2_rn(a.x, a.y);
    __half2 h1 = __floats2half2_rn(a.z, a.w);
    uint2 packed;
    packed.x = *(unsigned int*)&h0;
    packed.y = *(unsigned int*)&h1;
    *(uint2*)(attr_p + (size_t)p * E_IN + qi) = packed;
}

// ---------------- per-layer constants ----------------
__global__ __launch_bounds__(256) void make_wqe(const float* __restrict__ Wq,
                                                const float* __restrict__ bq,
                                                const float* __restrict__ We,
                                                float* __restrict__ Wqe,
                                                float* __restrict__ bqe) {
    int l = blockIdx.x / HID;
    int i = blockIdx.x % HID;
    int t = threadIdx.x;           // h*64+j
    int h = t >> 6, j = t & 63;
    const float* WqL = Wq + (size_t)l * HID * HC;
    const float* WeL = We + (size_t)l * HID * HC;
    float acc = 0.f;
    for (int c = 0; c < CH; c++)
        acc += WqL[i * HC + h * CH + c] * WeL[j * HC + h * CH + c];
    Wqe[(size_t)l * HID * HC + i * HC + t] = acc;
    if (i == 0) {
        const float* bqL = bq + l * HC;
        float accb = 0.f;
        for (int c = 0; c < CH; c++)
            accb += bqL[h * CH + c] * WeL[j * HC + h * CH + c];
        bqe[l * HC + t] = accb;
    }
}

__global__ __launch_bounds__(256) void make_wqe2(const float* __restrict__ Wqe,
                                                 const float* __restrict__ bqe,
                                                 const float* __restrict__ eW,
                                                 const float* __restrict__ eb,
                                                 float* __restrict__ Wqe2,
                                                 float* __restrict__ bqe2,
                                                 float* __restrict__ wqb,
                                                 float* __restrict__ bqb) {
    int l = blockIdx.x / HID, i = blockIdx.x % HID;
    int t = threadIdx.x;
    int h2 = t >> 6, m = t & 63;
    const float* Wr = Wqe + (size_t)l * HID * HC + i * HC + h2 * CH;  // [j]
    float acc = 0.f;
    for (int j = 0; j < HID; j++) acc += Wr[j] * eW[m * HID + j];
    Wqe2[(size_t)l * HID * HC + i * HC + t] = acc;
    if (m == 0) {
        float a = 0.f;
        for (int j = 0; j < HID; j++) a += Wr[j] * eb[j];
        wqb[l * HID * NH + i * NH + h2] = a;
    }
    if (i == 0) {
        const float* br = bqe + l * HC + h2 * CH;
        float a = 0.f;
        for (int j = 0; j < HID; j++) a += br[j] * eW[m * HID + j];
        bqe2[l * HC + t] = a;
        if (m == 0) {
            float bb = 0.f;
            for (int j = 0; j < HID; j++) bb += br[j] * eb[j];
            bqb[l * NH + h2] = bb;
        }
    }
}

__global__ __launch_bounds__(256) void make_weE(const float* __restrict__ eW,
                                                const float* __restrict__ eb,
                                                const float* __restrict__ We,
                                                float* __restrict__ WeE,
                                                float* __restrict__ beE) {
    int l = blockIdx.x / E_IN, m = blockIdx.x % E_IN;
    int t = threadIdx.x;
    const float* WeL = We + (size_t)l * HID * HC;
    float acc = 0.f;
    for (int j = 0; j < HID; j++) acc += eW[m * HID + j] * WeL[j * HC + t];
    WeE[(size_t)l * E_IN * HC + m * HC + t] = acc;
    if (m == 0) {
        float a = 0.f;
        for (int j = 0; j < HID; j++) a += eb[j] * WeL[j * HC + t];
        beE[l * HC + t] = a;
    }
}

// ---------------- per-layer node pre-pass (rank-indexed outputs) ----------------
// q,qw fp32 planar; k,v packed fp16 interleaved: kv[r][ (c>>2)*8 + (c&3) ] = k ch c,
// kv[r][ (c>>2)*8 + 4 + (c&3) ] = v ch c  (so gather lane l loads uint4 at l*8 halfs)
__global__ __launch_bounds__(256) void node_pre(const float* __restrict__ h,
        const int* __restrict__ node_order,
        const float* __restrict__ Wq, const float* __restrict__ bq,
        const float* __restrict__ Wk, const float* __restrict__ bk,
        const float* __restrict__ Wv, const float* __restrict__ bv,
        const float* __restrict__ Wqe2, const float* __restrict__ bqe2,
        const float* __restrict__ wqb, const float* __restrict__ bqb,
        const float* __restrict__ Ws, const float* __restrict__ bs,
        const float* __restrict__ g, const float* __restrict__ be,
        int do_ln,
        float* __restrict__ q, __half* __restrict__ kv,
        float* __restrict__ qw, float* __restrict__ skip, float* __restrict__ qb) {
    int t = threadIdx.x;
    int base = blockIdx.x * NPB;
    int lane = t & 63;
    __shared__ float zs[NPB][HID];
    __shared__ int nord[NPB];
    if (t < NPB) {
        int r = base + t;
        nord[t] = (r < N_NODES) ? node_order[r] : 0;
    }
    __syncthreads();
    for (int it = 0; it < NPB / 4; it++) {
        int m = (t >> 6) + it * 4;
        int r = base + m;
        float val = (r < N_NODES) ? h[nord[m] * HID + lane] : 0.f;
        if (do_ln) {
            float mu = val;
            for (int o = 32; o > 0; o >>= 1) mu += __shfl_xor(mu, o);
            mu *= (1.f / 64.f);
            float d = val - mu;
            float var = d * d;
            for (int o = 32; o > 0; o >>= 1) var += __shfl_xor(var, o);
            var *= (1.f / 64.f);
            val = fmaxf(d * rsqrtf(var + 1e-5f) * g[lane] + be[lane], 0.f);
        }
        zs[m][lane] = val;
    }
    __syncthreads();
    float aq[NPB], ak[NPB], av[NPB], aw[NPB], as_[NPB];
    float bqv = bq[t], bkv = bk[t], bvv = bv[t], bwv = bqe2[t];
    float bsv = (t < 64) ? bs[t] : 0.f;
#pragma unroll
    for (int m = 0; m < NPB; m++) { aq[m]=bqv; ak[m]=bkv; av[m]=bvv; aw[m]=bwv; as_[m]=bsv; }
    for (int i = 0; i < HID; i++) {
        float wq = Wq[i * HC + t], wk = Wk[i * HC + t];
        float wv = Wv[i * HC + t], wqe = Wqe2[i * HC + t];
        float wsv = (t < 64) ? Ws[i * HID + t] : 0.f;
#pragma unroll
        for (int m = 0; m < NPB; m++) {
            float z = zs[m][i];
            aq[m] += z * wq; ak[m] += z * wk; av[m] += z * wv;
            aw[m] += z * wqe; as_[m] += z * wsv;
        }
    }
    int kpos = (t >> 2) * 8 + (t & 3);
#pragma unroll
    for (int m = 0; m < NPB; m++) {
        int r = base + m;
        if (r >= N_NODES) break;
        size_t rb = (size_t)r * HC + t;   // planar fp32
        q[rb]  = aq[m];
        qw[rb] = aw[m];
        __half* kvrow = kv + (size_t)r * (2 * HC);
        kvrow[kpos]     = __float2half_rn(ak[m]);
        kvrow[kpos + 4] = __float2half_rn(av[m]);
        if (t < 64) skip[r * HID + t] = as_[m];
    }
    // qb[r][h] = zs . wqb[:,h] + bqb[h]
    if (t < NPB * NH) {
        int m = t >> 2, h4 = t & 3;
        int r = base + m;
        if (r < N_NODES) {
            float a = bqb[h4];
            for (int i = 0; i < HID; i++) a += zs[m][i] * wqb[i * NH + h4];
            qb[r * NH + h4] = a;
        }
    }
}

// ---------------- per-layer edge gather: 1 wave = 1 rank; quarter-wave = 1 head ----
// lane = h*16+i holds channels c = i*4..i*4+3 of head h
__global__ __launch_bounds__(256) void gather_edges(
        const int* __restrict__ new_rp,
        const int* __restrict__ srcrank_perm, const __half* __restrict__ attr_p,
        const __half* __restrict__ kv,
        const float* __restrict__ qb,
        float* q_numv,      // in: q planar, out: numv planar
        float* qw_numea,    // in: qw planar, out: numea planar
        float* __restrict__ den) {
    int wave = threadIdx.x >> 6;
    int lane = threadIdx.x & 63;
    int r = blockIdx.x * 4 + wave;
    if (r >= N_NODES) return;
    int e0 = new_rp[r], e1 = new_rp[r + 1];
    size_t nb = (size_t)r * HC;
    int qi = (lane & 15) * 4;
    int head = lane >> 4;
    const float4 qv4 = *(const float4*)(q_numv + nb + lane * 4);
    const float4 qw4 = *(const float4*)(qw_numea + nb + lane * 4);
    float qbh = qb[r * NH + head];
    float4 nv = make_float4(0.f, 0.f, 0.f, 0.f);
    float4 ne = make_float4(0.f, 0.f, 0.f, 0.f);
    float dsum = 0.f;
#pragma unroll 2
    for (int e = e0; e < e1; e++) {
        int s_ = srcrank_perm[e];
        uint2 araw = *(const uint2*)(attr_p + (size_t)e * E_IN + qi);
        uint4 kraw = *(const uint4*)(kv + (size_t)s_ * (2 * HC) + lane * 8);
        float2 a01 = __half22float2(*(__half2*)&araw.x);
        float2 a23 = __half22float2(*(__half2*)&araw.y);
        float2 k01 = __half22float2(*(__half2*)&kraw.x);
        float2 k23 = __half22float2(*(__half2*)&kraw.y);
        float2 v01 = __half22float2(*(__half2*)&kraw.z);
        float2 v23 = __half22float2(*(__half2*)&kraw.w);
        float rr = qv4.x * k01.x + qv4.y * k01.y + qv4.z * k23.x + qv4.w * k23.y
                 + qw4.x * a01.x + qw4.y * a01.y + qw4.z * a23.x + qw4.w * a23.y;
        rr += __shfl_xor(rr, 1);   // masks < 16 stay within the quarter-wave
        rr += __shfl_xor(rr, 2);
        rr += __shfl_xor(rr, 4);
        rr += __shfl_xor(rr, 8);
        float ex = __expf((rr + qbh) * 0.125f);
        nv.x += ex * v01.x; nv.y += ex * v01.y; nv.z += ex * v23.x; nv.w += ex * v23.y;
        ne.x += ex * a01.x; ne.y += ex * a01.y; ne.z += ex * a23.x; ne.w += ex * a23.y;
        dsum += ex;
    }
    *(float4*)(q_numv + nb + lane * 4) = nv;
    *(float4*)(qw_numea + nb + lane * 4) = ne;
    if ((lane & 15) == 0) den[r * NH + head] = dsum;
}

// ---------------- per-layer node post-pass (rank-indexed inputs) ----------------
__global__ __launch_bounds__(256) void node_post(
        const int* __restrict__ node_order,
        const float* __restrict__ numv, const float* __restrict__ numeat,
        const float* __restrict__ den, const float* __restrict__ WeE,
        const float* __restrict__ beE,
        const float* __restrict__ skip, float* __restrict__ h, int add_res) {
    int t = threadIdx.x;
    int h_ = t >> 6;
    int base = blockIdx.x * NPO;
    __shared__ float nes[NPO][HC];
    __shared__ float vals[NPO][HC];
    __shared__ int nord[NPO];
    if (t < NPO) {
        int r = base + t;
        nord[t] = (r < N_NODES) ? node_order[r] : 0;
    }
    for (int i = t; i < NPO * HC; i += 256) {
        int m = i >> 8;
        nes[m][i & 255] = numeat[(size_t)(base + m) * HC + (i & 255)];
    }
    __syncthreads();
    float acc[NPO];
#pragma unroll
    for (int m = 0; m < NPO; m++) acc[m] = 0.f;
    for (int j = 0; j < E_IN; j++) {
        float w = WeE[j * HC + t];
#pragma unroll
        for (int m = 0; m < NPO; m++) acc[m] += nes[m][h_ * CH + j] * w;
    }
    float bev = beE[t];
#pragma unroll
    for (int m = 0; m < NPO; m++) {
        int r = base + m;
        float dd = den[r * NH + h_];
        vals[m][t] = (numv[(size_t)r * HC + t] + acc[m] + dd * bev) / (dd + 1e-16f) * 0.25f;
    }
    __syncthreads();
    for (int it = 0; it < 2; it++) {
        int idx = t + it * 256;          // 8 nodes x 64 ch
        int m = idx >> 6, c2 = idx & 63;
        int r = base + m;
        if (r >= N_NODES) continue;
        int n = nord[m];
        float s = vals[m][c2] + vals[m][64 + c2] + vals[m][128 + c2] + vals[m][192 + c2];
        float val = s + skip[r * HID + c2];
        if (add_res) val += h[n * HID + c2];
        h[n * HID + c2] = val;
    }
}

// ---------------- final head ----------------
__global__ __launch_bounds__(64) void final_head(const float* __restrict__ h,
                                                 const float* __restrict__ g,
                                                 const float* __restrict__ b,
                                                 const float* __restrict__ W,
                                                 const float* __restrict__ bias,
                                                 float* __restrict__ out) {
    int n = blockIdx.x;
    int t = threadIdx.x;  // 64
    float val = h[n * HID + t];
    float mu = val;
    for (int o = 32; o > 0; o >>= 1) mu += __shfl_xor(mu, o);
    mu *= (1.f / 64.f);
    float d = val - mu;
    float var = d * d;
    for (int o = 32; o > 0; o >>= 1) var += __shfl_xor(var, o);
    var *= (1.f / 64.f);
    float z = fmaxf(d * rsqrtf(var + 1e-5f) * g[t] + b[t], 0.f);
    __shared__ float zs[HID];
    zs[t] = z;
    __syncthreads();
    if (t < OUT_DIM) {
        float acc = bias[t];
        for (int i = 0; i < HID; i++) acc += zs[i] * W[i * OUT_DIM + t];
        out[n * OUT_DIM + t] = acc;
    }
}

extern "C" void kernel_launch(void* const* d_in, const int* in_sizes, int n_in,
                              void* d_out, int out_size, void* d_ws, size_t ws_size,
                              hipStream_t stream) {
    const float* x      = (const float*)d_in[0];
    const int*   ei     = (const int*)d_in[1];
    const float* eattr  = (const float*)d_in[2];
    const float* node_W = (const float*)d_in[3];
    const float* node_b = (const float*)d_in[4];
    const float* eenc_W = (const float*)d_in[5];
    const float* eenc_b = (const float*)d_in[6];
    const float* Wq     = (const float*)d_in[7];
    const float* bq     = (const float*)d_in[8];
    const float* Wk     = (const float*)d_in[9];
    const float* bk     = (const float*)d_in[10];
    const float* Wv     = (const float*)d_in[11];
    const float* bv     = (const float*)d_in[12];
    const float* We     = (const float*)d_in[13];
    const float* Wskip  = (const float*)d_in[14];
    const float* bskip  = (const float*)d_in[15];
    const float* ln_g   = (const float*)d_in[16];
    const float* ln_b   = (const float*)d_in[17];
    const float* lin_W  = (const float*)d_in[18];
    const float* lin_b  = (const float*)d_in[19];
    float* out = (float*)d_out;

    const int* src = ei;            // edge_index[0]
    const int* dst = ei + N_EDGES;  // edge_index[1]

    float* ws = (float*)d_ws;
    // attr_p: fp16, occupies N_EDGES*E_IN/2 floats (10.24M floats)
    __half* attr_p = (__half*)ws; ws += (size_t)N_EDGES * E_IN / 2;
    float* Wqe    = (float*)attr_p;  // ALIAS: dead before permute_attr runs (1 MB < 41 MB)
    float* h    = ws; ws += N_NODES * HID;
    float* q    = ws; ws += (size_t)N_NODES * HC;      // -> numv (rank-indexed)
    float* qw   = ws; ws += (size_t)N_NODES * HC;      // -> numeat (rank-indexed)
    __half* kv  = (__half*)ws; ws += (size_t)N_NODES * HC;  // fp16 k+v packed (rank-idx)
    float* skip = ws; ws += N_NODES * HID;             // rank-indexed
    float* den  = ws; ws += N_NODES * NH;              // rank-indexed
    float* qb   = ws; ws += N_NODES * NH;              // rank-indexed
    float* bqe  = ws; ws += L_LAYERS * HC;
    float* Wqe2 = ws; ws += (size_t)L_LAYERS * HID * HC;
    float* bqe2 = ws; ws += L_LAYERS * HC;
    float* wqb  = ws; ws += L_LAYERS * HID * NH;
    float* bqb  = ws; ws += L_LAYERS * NH;
    float* WeE  = ws; ws += (size_t)L_LAYERS * E_IN * HC;
    float* beE  = ws; ws += L_LAYERS * HC;
    int* ip = (int*)ws;
    int* hist         = ip; ip += N_NODES;
    int* bins         = ip; ip += 256;
    int* curb         = ip; ip += 256;
    int* node_order   = ip; ip += N_NODES;
    int* rank_of      = ip; ip += N_NODES;
    int* deg_rank     = ip; ip += N_NODES;
    int* new_rp       = ip; ip += N_NODES + 4;
    int* cursor2      = ip; ip += N_NODES;
    int* srcrank_perm = ip; ip += N_EDGES;
    int* eid_of       = ip; ip += N_EDGES;

    node_enc<<<(N_NODES + 3) / 4, 256, 0, stream>>>(x, node_W, node_b, h);

    hipMemsetAsync(hist, 0, N_NODES * sizeof(int), stream);
    hipMemsetAsync(bins, 0, 256 * sizeof(int), stream);
    hist_dst<<<(N_EDGES + 255) / 256, 256, 0, stream>>>(dst, hist);
    bin_hist<<<(N_NODES + 255) / 256, 256, 0, stream>>>(hist, bins);
    scan_bins<<<1, 256, 0, stream>>>(bins, curb);
    assign_rank<<<(N_NODES + 255) / 256, 256, 0, stream>>>(hist, curb, node_order,
                                                           rank_of, deg_rank);
    scan_hist<<<1, 1024, 0, stream>>>(deg_rank, new_rp, cursor2);

    // per-layer constants (Wqe aliases attr_p -> must finish before permute_attr)
    make_wqe<<<L_LAYERS * HID, 256, 0, stream>>>(Wq, bq, We, Wqe, bqe);
    make_wqe2<<<L_LAYERS * HID, 256, 0, stream>>>(Wqe, bqe, eenc_W, eenc_b,
                                                  Wqe2, bqe2, wqb, bqb);
    make_weE<<<L_LAYERS * E_IN, 256, 0, stream>>>(eenc_W, eenc_b, We, WeE, beE);

    compute_pos<<<(N_EDGES + 255) / 256, 256, 0, stream>>>(src, dst, rank_of, cursor2,
                                                           eid_of, srcrank_perm);
    permute_attr<<<N_EDGES / 16, 256, 0, stream>>>(eid_of, eattr, attr_p);

    for (int l = 0; l < L_LAYERS; l++) {
        node_pre<<<(N_NODES + NPB - 1) / NPB, 256, 0, stream>>>(
            h, node_order,
            Wq + (size_t)l * HID * HC, bq + l * HC,
            Wk + (size_t)l * HID * HC, bk + l * HC,
            Wv + (size_t)l * HID * HC, bv + l * HC,
            Wqe2 + (size_t)l * HID * HC, bqe2 + l * HC,
            wqb + l * HID * NH, bqb + l * NH,
            Wskip + (size_t)l * HID * HID, bskip + l * HID,
            ln_g + l * HID, ln_b + l * HID,
            (l > 0) ? 1 : 0,
            q, kv, qw, skip, qb);
        gather_edges<<<(N_NODES + 3) / 4, 256, 0, stream>>>(
            new_rp, srcrank_perm, attr_p, kv, qb, q, qw, den);
        node_post<<<(N_NODES + NPO - 1) / NPO, 256, 0, stream>>>(
            node_order, q, qw, den, WeE + (size_t)l * E_IN * HC, beE + l * HC,
            skip, h, (l > 0) ? 1 : 0);
    }

    final_head<<<N_NODES, 64, 0, stream>>>(h, ln_g, ln_b, lin_W, lin_b, out);
}

// Round 6
// 846.038 us; speedup vs baseline: 1.5861x; 1.2051x over previous
//
#include <hip/hip_runtime.h>
#include <hip/hip_fp16.h>
#include <math.h>

#define N_NODES 20000
#define N_EDGES 320000
#define F_IN    128
#define E_IN    64
#define HID     64
#define NH      4
#define CH      64
#define HC      256   // NH*CH
#define L_LAYERS 4
#define OUT_DIM 32
#define NPO     8     // nodes per block in node_post
#define WCOLS   1088  // 256 q + 256 k + 256 v + 256 qw + 64 skip

typedef _Float16 half8 __attribute__((ext_vector_type(8)));
typedef float f32x4 __attribute__((ext_vector_type(4)));

// ---------------- one-time: node encoder ----------------
__global__ __launch_bounds__(256) void node_enc(const float* __restrict__ x,
                                                const float* __restrict__ W,
                                                const float* __restrict__ b,
                                                float* __restrict__ h) {
    int base_node = blockIdx.x * 4;
    int t = threadIdx.x;
    __shared__ float xs[4][F_IN];
    for (int i = t; i < 4 * F_IN; i += 256) {
        int nn = base_node + i / F_IN;
        xs[i / F_IN][i % F_IN] = (nn < N_NODES) ? x[nn * F_IN + (i % F_IN)] : 0.f;
    }
    __syncthreads();
    int node = base_node + t / 64;
    int col  = t & 63;
    if (node >= N_NODES) return;
    float acc = b[col];
    const float* xr = xs[t / 64];
    for (int i = 0; i < F_IN; i++) acc += xr[i] * W[i * HID + col];
    h[node * HID + col] = acc;
}

// ---------------- CSR build with degree-descending node order ----------------
__global__ __launch_bounds__(256) void hist_dst(const int* __restrict__ dst,
                                                int* __restrict__ hist) {
    int e = blockIdx.x * 256 + threadIdx.x;
    if (e < N_EDGES) atomicAdd(&hist[dst[e]], 1);
}

__global__ __launch_bounds__(256) void bin_hist(const int* __restrict__ hist,
                                                int* __restrict__ bins) {
    int n = blockIdx.x * 256 + threadIdx.x;
    if (n >= N_NODES) return;
    int d = hist[n]; if (d > 255) d = 255;
    atomicAdd(&bins[d], 1);
}

__global__ __launch_bounds__(256) void scan_bins(const int* __restrict__ bins,
                                                 int* __restrict__ curb) {
    __shared__ int s[256];
    int t = threadIdx.x;
    s[t] = bins[t];
    __syncthreads();
    int acc = 0;
    for (int b = t + 1; b < 256; b++) acc += s[b];
    curb[t] = acc;
}

__global__ __launch_bounds__(256) void assign_rank(const int* __restrict__ hist,
                                                   int* __restrict__ curb,
                                                   int* __restrict__ node_order,
                                                   int* __restrict__ rank_of,
                                                   int* __restrict__ deg_rank) {
    int n = blockIdx.x * 256 + threadIdx.x;
    if (n >= N_NODES) return;
    int d = hist[n];
    int b = d > 255 ? 255 : d;
    int r = atomicAdd(&curb[b], 1);
    node_order[r] = n;
    rank_of[n] = r;
    deg_rank[r] = d;
}

__global__ __launch_bounds__(1024) void scan_hist(const int* __restrict__ arr,
                                                  int* __restrict__ row_ptr,
                                                  int* __restrict__ cursor) {
    __shared__ int sums[1024];
    const int CHUNK = 20;  // 1024*20 = 20480 >= 20000
    int t = threadIdx.x;
    int base = t * CHUNK;
    int local[CHUNK];
    int s = 0;
    for (int i = 0; i < CHUNK; i++) {
        int idx = base + i;
        int vv = (idx < N_NODES) ? arr[idx] : 0;
        local[i] = s;
        s += vv;
    }
    sums[t] = s;
    __syncthreads();
    for (int off = 1; off < 1024; off <<= 1) {
        int v = (t >= off) ? sums[t - off] : 0;
        __syncthreads();
        sums[t] += v;
        __syncthreads();
    }
    int excl = (t == 0) ? 0 : sums[t - 1];
    for (int i = 0; i < CHUNK; i++) {
        int idx = base + i;
        if (idx < N_NODES) {
            int p = excl + local[i];
            row_ptr[idx] = p;
            cursor[idx] = p;
        }
    }
    if (t == 1023) row_ptr[N_NODES] = sums[1023];
}

// phase A: positions only (int traffic)
__global__ __launch_bounds__(256) void compute_pos(const int* __restrict__ src,
                                                   const int* __restrict__ dst,
                                                   const int* __restrict__ rank_of,
                                                   int* __restrict__ cursor2,
                                                   int* __restrict__ eid_of,
                                                   int* __restrict__ srcrank_perm) {
    int e = blockIdx.x * 256 + threadIdx.x;
    if (e >= N_EDGES) return;
    int r = rank_of[dst[e]];
    int pos = atomicAdd(&cursor2[r], 1);
    eid_of[pos] = e;
    srcrank_perm[pos] = rank_of[src[e]];
}

// phase B: gather-form attr permute + fp16 convert
__global__ __launch_bounds__(256) void permute_attr(const int* __restrict__ eid_of,
                                                    const float* __restrict__ eattr,
                                                    __half* __restrict__ attr_p) {
    int t = threadIdx.x;
    int wave = t >> 6, lane = t & 63;
    int p = blockIdx.x * 16 + wave * 4 + (lane >> 4);
    if (p >= N_EDGES) return;
    int e = eid_of[p];
    int qi = (lane & 15) * 4;
    float4 a = *(const float4*)(eattr + (size_t)e * E_IN + qi);
    __half2 h0 = __floats2half2_rn(a.x, a.y);
    __half2 h1 = __floats2half2_rn(a.z, a.w);
    uint2 packed;
    packed.x = *(unsigned int*)&h0;
    packed.y = *(unsigned int*)&h1;
    *(uint2*)(attr_p + (size_t)p * E_IN + qi) = packed;
}

// ---------------- per-layer constants ----------------
__global__ __launch_bounds__(256) void make_wqe(const float* __restrict__ Wq,
                                                const float* __restrict__ bq,
                                                const float* __restrict__ We,
                                                float* __restrict__ Wqe,
                                                float* __restrict__ bqe) {
    int l = blockIdx.x / HID;
    int i = blockIdx.x % HID;
    int t = threadIdx.x;           // h*64+j
    int h = t >> 6, j = t & 63;
    const float* WqL = Wq + (size_t)l * HID * HC;
    const float* WeL = We + (size_t)l * HID * HC;
    float acc = 0.f;
    for (int c = 0; c < CH; c++)
        acc += WqL[i * HC + h * CH + c] * WeL[j * HC + h * CH + c];
    Wqe[(size_t)l * HID * HC + i * HC + t] = acc;
    if (i == 0) {
        const float* bqL = bq + l * HC;
        float accb = 0.f;
        for (int c = 0; c < CH; c++)
            accb += bqL[h * CH + c] * WeL[j * HC + h * CH + c];
        bqe[l * HC + t] = accb;
    }
}

__global__ __launch_bounds__(256) void make_wqe2(const float* __restrict__ Wqe,
                                                 const float* __restrict__ bqe,
                                                 const float* __restrict__ eW,
                                                 const float* __restrict__ eb,
                                                 float* __restrict__ Wqe2,
                                                 float* __restrict__ bqe2,
                                                 float* __restrict__ wqb,
                                                 float* __restrict__ bqb) {
    int l = blockIdx.x / HID, i = blockIdx.x % HID;
    int t = threadIdx.x;
    int h2 = t >> 6, m = t & 63;
    const float* Wr = Wqe + (size_t)l * HID * HC + i * HC + h2 * CH;  // [j]
    float acc = 0.f;
    for (int j = 0; j < HID; j++) acc += Wr[j] * eW[m * HID + j];
    Wqe2[(size_t)l * HID * HC + i * HC + t] = acc;
    if (m == 0) {
        float a = 0.f;
        for (int j = 0; j < HID; j++) a += Wr[j] * eb[j];
        wqb[l * HID * NH + i * NH + h2] = a;
    }
    if (i == 0) {
        const float* br = bqe + l * HC + h2 * CH;
        float a = 0.f;
        for (int j = 0; j < HID; j++) a += br[j] * eW[m * HID + j];
        bqe2[l * HC + t] = a;
        if (m == 0) {
            float bb = 0.f;
            for (int j = 0; j < HID; j++) bb += br[j] * eb[j];
            bqb[l * NH + h2] = bb;
        }
    }
}

__global__ __launch_bounds__(256) void make_weE(const float* __restrict__ eW,
                                                const float* __restrict__ eb,
                                                const float* __restrict__ We,
                                                float* __restrict__ WeE,
                                                float* __restrict__ beE) {
    int l = blockIdx.x / E_IN, m = blockIdx.x % E_IN;
    int t = threadIdx.x;
    const float* WeL = We + (size_t)l * HID * HC;
    float acc = 0.f;
    for (int j = 0; j < HID; j++) acc += eW[m * HID + j] * WeL[j * HC + t];
    WeE[(size_t)l * E_IN * HC + m * HC + t] = acc;
    if (m == 0) {
        float a = 0.f;
        for (int j = 0; j < HID; j++) a += eb[j] * WeL[j * HC + t];
        beE[l * HC + t] = a;
    }
}

// W16T[l][col][i] = f16 of column `col` of the concatenated [64 x 1088] weight
// block [Wq | Wk | Wv | Wqe2 | Wskip]; biasc = concatenated fp32 biases.
__global__ __launch_bounds__(256) void make_w16(
        const float* __restrict__ Wq, const float* __restrict__ Wk,
        const float* __restrict__ Wv, const float* __restrict__ Wqe2,
        const float* __restrict__ Wsk,
        const float* __restrict__ bq, const float* __restrict__ bk,
        const float* __restrict__ bv, const float* __restrict__ bqe2,
        const float* __restrict__ bsk,
        _Float16* __restrict__ W16T, float* __restrict__ biasc) {
    int l = blockIdx.x / 272;
    int cg = blockIdx.x % 272;
    int col = cg * 4 + (threadIdx.x >> 6);
    int i = threadIdx.x & 63;
    float w, b;
    if (col < 256)       { w = Wq[(size_t)l*HID*HC + i*HC + col];          b = bq[l*HC + col]; }
    else if (col < 512)  { w = Wk[(size_t)l*HID*HC + i*HC + col-256];      b = bk[l*HC + col-256]; }
    else if (col < 768)  { w = Wv[(size_t)l*HID*HC + i*HC + col-512];      b = bv[l*HC + col-512]; }
    else if (col < 1024) { w = Wqe2[(size_t)l*HID*HC + i*HC + col-768];    b = bqe2[l*HC + col-768]; }
    else                 { w = Wsk[(size_t)l*HID*HID + i*HID + col-1024];  b = bsk[l*HID + col-1024]; }
    W16T[((size_t)l * WCOLS + col) * 64 + i] = (_Float16)w;
    if (i == 0) biasc[l * WCOLS + col] = b;
}

// ---------------- per-layer node pre-pass: MFMA f16 GEMM ----------------
// 32 nodes/block; z = (do_ln ? relu(LN(h)) : h) as f16 in LDS;
// [32 x 64] @ [64 x 1088] via v_mfma_f32_16x16x32_f16; epilogue routes cols:
// 0..255 -> q fp32 planar; 256..511 -> k (packed f16 kv); 512..767 -> v;
// 768..1023 -> qw fp32 planar; 1024..1087 -> skip fp32.
__global__ __launch_bounds__(256) void node_pre(const float* __restrict__ h,
        const int* __restrict__ node_order,
        const _Float16* __restrict__ W16T, const float* __restrict__ biasc,
        const float* __restrict__ wqb, const float* __restrict__ bqb,
        const float* __restrict__ g, const float* __restrict__ be,
        int do_ln,
        float* __restrict__ q, _Float16* __restrict__ kv,
        float* __restrict__ qw, float* __restrict__ skip,
        float* __restrict__ qb) {
    int t = threadIdx.x;
    int wave = t >> 6, lane = t & 63;
    int base = blockIdx.x * 32;
    __shared__ _Float16 zs[32][72];   // +8 halfs pad -> 2-way LDS aliasing (free)
    __shared__ int nord[32];
    if (t < 32) nord[t] = node_order[base + t];
    __syncthreads();
    // LN phase: wave w handles nodes m = it*4 + w
    for (int it = 0; it < 8; it++) {
        int m = it * 4 + wave;
        float val = h[nord[m] * HID + lane];
        if (do_ln) {
            float mu = val;
            for (int o = 32; o > 0; o >>= 1) mu += __shfl_xor(mu, o);
            mu *= (1.f / 64.f);
            float d = val - mu;
            float var = d * d;
            for (int o = 32; o > 0; o >>= 1) var += __shfl_xor(var, o);
            var *= (1.f / 64.f);
            val = fmaxf(d * rsqrtf(var + 1e-5f) * g[lane] + be[lane], 0.f);
        }
        zs[m][lane] = (_Float16)val;
    }
    __syncthreads();
    // qb[r][h4] = z . wqb[:,h4] + bqb[h4]  (fp32, threads 0..127)
    if (t < 128) {
        int m = t >> 2, h4 = t & 3;
        float a = bqb[h4];
        for (int i = 0; i < HID; i++) a += (float)zs[m][i] * wqb[i * NH + h4];
        qb[(base + m) * NH + h4] = a;
    }
    // MFMA phase
    int quad = lane >> 4;
    int mrow = lane & 15;
    half8 a00 = *(const half8*)&zs[mrow][quad * 8];
    half8 a01 = *(const half8*)&zs[mrow][32 + quad * 8];
    half8 a10 = *(const half8*)&zs[16 + mrow][quad * 8];
    half8 a11 = *(const half8*)&zs[16 + mrow][32 + quad * 8];
    int colwave = wave * 272;
    for (int tile = 0; tile < 17; tile++) {
        int colb = colwave + tile * 16;
        int col = colb + mrow;
        const _Float16* wrow = W16T + (size_t)col * 64;
        half8 b0 = *(const half8*)(wrow + quad * 8);
        half8 b1 = *(const half8*)(wrow + 32 + quad * 8);
        f32x4 acc0 = {0.f, 0.f, 0.f, 0.f};
        f32x4 acc1 = {0.f, 0.f, 0.f, 0.f};
        acc0 = __builtin_amdgcn_mfma_f32_16x16x32_f16(a00, b0, acc0, 0, 0, 0);
        acc0 = __builtin_amdgcn_mfma_f32_16x16x32_f16(a01, b1, acc0, 0, 0, 0);
        acc1 = __builtin_amdgcn_mfma_f32_16x16x32_f16(a10, b0, acc1, 0, 0, 0);
        acc1 = __builtin_amdgcn_mfma_f32_16x16x32_f16(a11, b1, acc1, 0, 0, 0);
        float bi = biasc[col];
        int seg = colb >> 8;           // wave-uniform per tile
        int r0 = base + quad * 4;
#pragma unroll
        for (int reg = 0; reg < 4; reg++) {
            float v0 = acc0[reg] + bi;
            float v1 = acc1[reg] + bi;
            int ra = r0 + reg, rb = ra + 16;
            if (seg == 0) {
                q[(size_t)ra * HC + col] = v0;
                q[(size_t)rb * HC + col] = v1;
            } else if (seg == 1) {
                int c = col - 256, kp = (c >> 2) * 8 + (c & 3);
                kv[(size_t)ra * 512 + kp] = (_Float16)v0;
                kv[(size_t)rb * 512 + kp] = (_Float16)v1;
            } else if (seg == 2) {
                int c = col - 512, kp = (c >> 2) * 8 + (c & 3) + 4;
                kv[(size_t)ra * 512 + kp] = (_Float16)v0;
                kv[(size_t)rb * 512 + kp] = (_Float16)v1;
            } else if (seg == 3) {
                int c = col - 768;
                qw[(size_t)ra * HC + c] = v0;
                qw[(size_t)rb * HC + c] = v1;
            } else {
                int c = col - 1024;
                skip[ra * HID + c] = v0;
                skip[rb * HID + c] = v1;
            }
        }
    }
}

// ---------------- per-layer edge gather: 1 wave = 1 rank; quarter-wave = 1 head ----
__global__ __launch_bounds__(256) void gather_edges(
        const int* __restrict__ new_rp,
        const int* __restrict__ srcrank_perm, const __half* __restrict__ attr_p,
        const __half* __restrict__ kv,
        const float* __restrict__ qb,
        float* q_numv,      // in: q planar, out: numv planar
        float* qw_numea,    // in: qw planar, out: numea planar
        float* __restrict__ den) {
    int wave = threadIdx.x >> 6;
    int lane = threadIdx.x & 63;
    int r = blockIdx.x * 4 + wave;
    if (r >= N_NODES) return;
    int e0 = new_rp[r], e1 = new_rp[r + 1];
    size_t nb = (size_t)r * HC;
    int qi = (lane & 15) * 4;
    int head = lane >> 4;
    const float4 qv4 = *(const float4*)(q_numv + nb + lane * 4);
    const float4 qw4 = *(const float4*)(qw_numea + nb + lane * 4);
    float qbh = qb[r * NH + head];
    float4 nv = make_float4(0.f, 0.f, 0.f, 0.f);
    float4 ne = make_float4(0.f, 0.f, 0.f, 0.f);
    float dsum = 0.f;
#pragma unroll 2
    for (int e = e0; e < e1; e++) {
        int s_ = srcrank_perm[e];
        uint2 araw = *(const uint2*)(attr_p + (size_t)e * E_IN + qi);
        uint4 kraw = *(const uint4*)(kv + (size_t)s_ * (2 * HC) + lane * 8);
        float2 a01 = __half22float2(*(__half2*)&araw.x);
        float2 a23 = __half22float2(*(__half2*)&araw.y);
        float2 k01 = __half22float2(*(__half2*)&kraw.x);
        float2 k23 = __half22float2(*(__half2*)&kraw.y);
        float2 v01 = __half22float2(*(__half2*)&kraw.z);
        float2 v23 = __half22float2(*(__half2*)&kraw.w);
        float rr = qv4.x * k01.x + qv4.y * k01.y + qv4.z * k23.x + qv4.w * k23.y
                 + qw4.x * a01.x + qw4.y * a01.y + qw4.z * a23.x + qw4.w * a23.y;
        rr += __shfl_xor(rr, 1);
        rr += __shfl_xor(rr, 2);
        rr += __shfl_xor(rr, 4);
        rr += __shfl_xor(rr, 8);
        float ex = __expf((rr + qbh) * 0.125f);
        nv.x += ex * v01.x; nv.y += ex * v01.y; nv.z += ex * v23.x; nv.w += ex * v23.y;
        ne.x += ex * a01.x; ne.y += ex * a01.y; ne.z += ex * a23.x; ne.w += ex * a23.y;
        dsum += ex;
    }
    *(float4*)(q_numv + nb + lane * 4) = nv;
    *(float4*)(qw_numea + nb + lane * 4) = ne;
    if ((lane & 15) == 0) den[r * NH + head] = dsum;
}

// ---------------- per-layer node post-pass (rank-indexed inputs) ----------------
__global__ __launch_bounds__(256) void node_post(
        const int* __restrict__ node_order,
        const float* __restrict__ numv, const float* __restrict__ numeat,
        const float* __restrict__ den, const float* __restrict__ WeE,
        const float* __restrict__ beE,
        const float* __restrict__ skip, float* __restrict__ h, int add_res) {
    int t = threadIdx.x;
    int h_ = t >> 6;
    int base = blockIdx.x * NPO;
    __shared__ float nes[NPO][HC];
    __shared__ float vals[NPO][HC];
    __shared__ int nord[NPO];
    if (t < NPO) {
        int r = base + t;
        nord[t] = (r < N_NODES) ? node_order[r] : 0;
    }
    for (int i = t; i < NPO * HC; i += 256) {
        int m = i >> 8;
        nes[m][i & 255] = numeat[(size_t)(base + m) * HC + (i & 255)];
    }
    __syncthreads();
    float acc[NPO];
#pragma unroll
    for (int m = 0; m < NPO; m++) acc[m] = 0.f;
    for (int j = 0; j < E_IN; j++) {
        float w = WeE[j * HC + t];
#pragma unroll
        for (int m = 0; m < NPO; m++) acc[m] += nes[m][h_ * CH + j] * w;
    }
    float bev = beE[t];
#pragma unroll
    for (int m = 0; m < NPO; m++) {
        int r = base + m;
        float dd = den[r * NH + h_];
        vals[m][t] = (numv[(size_t)r * HC + t] + acc[m] + dd * bev) / (dd + 1e-16f) * 0.25f;
    }
    __syncthreads();
    for (int it = 0; it < 2; it++) {
        int idx = t + it * 256;          // 8 nodes x 64 ch
        int m = idx >> 6, c2 = idx & 63;
        int r = base + m;
        if (r >= N_NODES) continue;
        int n = nord[m];
        float s = vals[m][c2] + vals[m][64 + c2] + vals[m][128 + c2] + vals[m][192 + c2];
        float val = s + skip[r * HID + c2];
        if (add_res) val += h[n * HID + c2];
        h[n * HID + c2] = val;
    }
}

// ---------------- final head ----------------
__global__ __launch_bounds__(64) void final_head(const float* __restrict__ h,
                                                 const float* __restrict__ g,
                                                 const float* __restrict__ b,
                                                 const float* __restrict__ W,
                                                 const float* __restrict__ bias,
                                                 float* __restrict__ out) {
    int n = blockIdx.x;
    int t = threadIdx.x;  // 64
    float val = h[n * HID + t];
    float mu = val;
    for (int o = 32; o > 0; o >>= 1) mu += __shfl_xor(mu, o);
    mu *= (1.f / 64.f);
    float d = val - mu;
    float var = d * d;
    for (int o = 32; o > 0; o >>= 1) var += __shfl_xor(var, o);
    var *= (1.f / 64.f);
    float z = fmaxf(d * rsqrtf(var + 1e-5f) * g[t] + b[t], 0.f);
    __shared__ float zs[HID];
    zs[t] = z;
    __syncthreads();
    if (t < OUT_DIM) {
        float acc = bias[t];
        for (int i = 0; i < HID; i++) acc += zs[i] * W[i * OUT_DIM + t];
        out[n * OUT_DIM + t] = acc;
    }
}

extern "C" void kernel_launch(void* const* d_in, const int* in_sizes, int n_in,
                              void* d_out, int out_size, void* d_ws, size_t ws_size,
                              hipStream_t stream) {
    const float* x      = (const float*)d_in[0];
    const int*   ei     = (const int*)d_in[1];
    const float* eattr  = (const float*)d_in[2];
    const float* node_W = (const float*)d_in[3];
    const float* node_b = (const float*)d_in[4];
    const float* eenc_W = (const float*)d_in[5];
    const float* eenc_b = (const float*)d_in[6];
    const float* Wq     = (const float*)d_in[7];
    const float* bq     = (const float*)d_in[8];
    const float* Wk     = (const float*)d_in[9];
    const float* bk     = (const float*)d_in[10];
    const float* Wv     = (const float*)d_in[11];
    const float* bv     = (const float*)d_in[12];
    const float* We     = (const float*)d_in[13];
    const float* Wskip  = (const float*)d_in[14];
    const float* bskip  = (const float*)d_in[15];
    const float* ln_g   = (const float*)d_in[16];
    const float* ln_b   = (const float*)d_in[17];
    const float* lin_W  = (const float*)d_in[18];
    const float* lin_b  = (const float*)d_in[19];
    float* out = (float*)d_out;

    const int* src = ei;            // edge_index[0]
    const int* dst = ei + N_EDGES;  // edge_index[1]

    float* ws = (float*)d_ws;
    __half* attr_p = (__half*)ws; ws += (size_t)N_EDGES * E_IN / 2;
    float* Wqe    = (float*)attr_p;  // ALIAS: dead before permute_attr runs
    float* h    = ws; ws += N_NODES * HID;
    float* q    = ws; ws += (size_t)N_NODES * HC;      // -> numv (rank-indexed)
    float* qw   = ws; ws += (size_t)N_NODES * HC;      // -> numeat (rank-indexed)
    _Float16* kv = (_Float16*)ws; ws += (size_t)N_NODES * HC;  // f16 k+v packed
    float* skip = ws; ws += N_NODES * HID;             // rank-indexed
    float* den  = ws; ws += N_NODES * NH;              // rank-indexed
    float* qb   = ws; ws += N_NODES * NH;              // rank-indexed
    float* bqe  = ws; ws += L_LAYERS * HC;
    float* Wqe2 = ws; ws += (size_t)L_LAYERS * HID * HC;
    float* bqe2 = ws; ws += L_LAYERS * HC;
    float* wqb  = ws; ws += L_LAYERS * HID * NH;
    float* bqb  = ws; ws += L_LAYERS * NH;
    float* WeE  = ws; ws += (size_t)L_LAYERS * E_IN * HC;
    float* beE  = ws; ws += L_LAYERS * HC;
    _Float16* W16T = (_Float16*)ws; ws += (size_t)L_LAYERS * WCOLS * HID / 2;
    float* biasc = ws; ws += L_LAYERS * WCOLS;
    int* ip = (int*)ws;
    int* hist         = ip; ip += N_NODES;
    int* bins         = ip; ip += 256;
    int* curb         = ip; ip += 256;
    int* node_order   = ip; ip += N_NODES;
    int* rank_of      = ip; ip += N_NODES;
    int* deg_rank     = ip; ip += N_NODES;
    int* new_rp       = ip; ip += N_NODES + 4;
    int* cursor2      = ip; ip += N_NODES;
    int* srcrank_perm = ip; ip += N_EDGES;
    int* eid_of       = ip; ip += N_EDGES;

    node_enc<<<(N_NODES + 3) / 4, 256, 0, stream>>>(x, node_W, node_b, h);

    hipMemsetAsync(hist, 0, N_NODES * sizeof(int), stream);
    hipMemsetAsync(bins, 0, 256 * sizeof(int), stream);
    hist_dst<<<(N_EDGES + 255) / 256, 256, 0, stream>>>(dst, hist);
    bin_hist<<<(N_NODES + 255) / 256, 256, 0, stream>>>(hist, bins);
    scan_bins<<<1, 256, 0, stream>>>(bins, curb);
    assign_rank<<<(N_NODES + 255) / 256, 256, 0, stream>>>(hist, curb, node_order,
                                                           rank_of, deg_rank);
    scan_hist<<<1, 1024, 0, stream>>>(deg_rank, new_rp, cursor2);

    // per-layer constants (Wqe aliases attr_p -> must finish before permute_attr)
    make_wqe<<<L_LAYERS * HID, 256, 0, stream>>>(Wq, bq, We, Wqe, bqe);
    make_wqe2<<<L_LAYERS * HID, 256, 0, stream>>>(Wqe, bqe, eenc_W, eenc_b,
                                                  Wqe2, bqe2, wqb, bqb);
    make_weE<<<L_LAYERS * E_IN, 256, 0, stream>>>(eenc_W, eenc_b, We, WeE, beE);
    make_w16<<<L_LAYERS * 272, 256, 0, stream>>>(Wq, Wk, Wv, Wqe2, Wskip,
                                                 bq, bk, bv, bqe2, bskip,
                                                 W16T, biasc);

    compute_pos<<<(N_EDGES + 255) / 256, 256, 0, stream>>>(src, dst, rank_of, cursor2,
                                                           eid_of, srcrank_perm);
    permute_attr<<<N_EDGES / 16, 256, 0, stream>>>(eid_of, eattr, attr_p);

    for (int l = 0; l < L_LAYERS; l++) {
        node_pre<<<N_NODES / 32, 256, 0, stream>>>(
            h, node_order,
            W16T + (size_t)l * WCOLS * HID, biasc + l * WCOLS,
            wqb + l * HID * NH, bqb + l * NH,
            ln_g + l * HID, ln_b + l * HID,
            (l > 0) ? 1 : 0,
            q, kv, qw, skip, qb);
        gather_edges<<<(N_NODES + 3) / 4, 256, 0, stream>>>(
            new_rp, srcrank_perm, attr_p, (const __half*)kv, qb, q, qw, den);
        node_post<<<(N_NODES + NPO - 1) / NPO, 256, 0, stream>>>(
            node_order, q, qw, den, WeE + (size_t)l * E_IN * HC, beE + l * HC,
            skip, h, (l > 0) ? 1 : 0);
    }

    final_head<<<N_NODES, 64, 0, stream>>>(h, ln_g, ln_b, lin_W, lin_b, out);
}